// Round 1
// baseline (4417.177 us; speedup 1.0000x reference)
//
#include <hip/hip_runtime.h>
#include <math.h>

#define S_LEN 2048
#define NHEAD 16
#define DHEAD 64
#define DMODEL 1024
#define NBATCH 2

// ---------------------------------------------------------------------------
// Generic fp32 GEMM: C[M,N] = A[M,K] @ B[K,N], row-major, all dims % 64 == 0.
// 64x64 block tile, BK=16, 256 threads, 4x4 per-thread micro-tile.
// ---------------------------------------------------------------------------
__global__ __launch_bounds__(256) void gemm64(const float* __restrict__ A,
                                              const float* __restrict__ B,
                                              float* __restrict__ C,
                                              int M, int N, int K) {
    __shared__ float As[16][68];   // transposed A tile, +pad
    __shared__ float Bs[16][68];
    const int tid = threadIdx.x;
    const int row = tid >> 4;      // 0..15
    const int col = tid & 15;      // 0..15
    const int bm = blockIdx.y * 64;
    const int bn = blockIdx.x * 64;

    float acc[4][4] = {};

    for (int k0 = 0; k0 < K; k0 += 16) {
        // A tile: 64 rows x 16 k; each thread loads 4 consecutive k (float4)
        {
            int a_idx = tid * 4;
            int ar = a_idx >> 4;          // 0..63
            int ak = a_idx & 15;          // 0,4,8,12
            float4 av = *(const float4*)(A + (size_t)(bm + ar) * K + k0 + ak);
            As[ak + 0][ar] = av.x;
            As[ak + 1][ar] = av.y;
            As[ak + 2][ar] = av.z;
            As[ak + 3][ar] = av.w;
        }
        // B tile: 16 k x 64 n; float4 load + float4 LDS store
        {
            int b_idx = tid * 4;
            int bk = b_idx >> 6;          // 0..15
            int bnn = b_idx & 63;         // 0,4,...,60
            float4 bv = *(const float4*)(B + (size_t)(k0 + bk) * N + bn + bnn);
            *(float4*)&Bs[bk][bnn] = bv;
        }
        __syncthreads();
        #pragma unroll
        for (int k = 0; k < 16; ++k) {
            float4 a = *(const float4*)&As[k][row * 4];
            float4 b = *(const float4*)&Bs[k][col * 4];
            float af[4] = {a.x, a.y, a.z, a.w};
            float bf[4] = {b.x, b.y, b.z, b.w};
            #pragma unroll
            for (int i = 0; i < 4; ++i)
                #pragma unroll
                for (int j = 0; j < 4; ++j)
                    acc[i][j] = fmaf(af[i], bf[j], acc[i][j]);
        }
        __syncthreads();
    }
    #pragma unroll
    for (int i = 0; i < 4; ++i) {
        float4 v = make_float4(acc[i][0], acc[i][1], acc[i][2], acc[i][3]);
        *(float4*)(C + (size_t)(bm + row * 4 + i) * N + bn + col * 4) = v;
    }
}

// ---------------------------------------------------------------------------
// Fused TXL attention, flash-style online softmax.
// Grid: (S/16, B*NHEAD). Block: 256 threads = 16 rows x 16 cols per tile step.
// rel-shift handled analytically:
//   j<=i   -> rr_q[i]   . r_k[S-1-i+j]
//   j==i+1 -> 0
//   j>=i+2 -> rr_q[i+1] . r_k[j-i-2]
// ---------------------------------------------------------------------------
__global__ __launch_bounds__(256) void attn_kernel(
    const float* __restrict__ wh,    // [B, S, 3*DMODEL] : q | k | v
    const float* __restrict__ rk,    // [S, DMODEL]      : (rel_pos @ W_rel)
    const float* __restrict__ rwb,   // [NHEAD*DHEAD]
    const float* __restrict__ rrb,   // [NHEAD*DHEAD]
    const int*   __restrict__ mask,  // [B, S], nonzero = masked
    float* __restrict__ ctx)         // [B, S, DMODEL]
{
    const int tid = threadIdx.x;
    const int ty = tid >> 4;         // query row within tile
    const int tx = tid & 15;         // key col within tile
    const int bn = blockIdx.y;
    const int b = bn >> 4, n = bn & 15;
    const int t0 = blockIdx.x * 16;

    __shared__ float qrw[16][68];
    __shared__ float qrr[17][68];    // +1 row: shift uses rr_q[i+1]
    __shared__ float Ks[16][68];
    __shared__ float Vs[16][68];
    __shared__ float Ps[16][17];

    // stage q rows (17 rows for qrr, 16 for qrw)
    for (int idx = tid; idx < 17 * 64; idx += 256) {
        int r = idx >> 6, d = idx & 63;
        int gi = t0 + r;
        if (gi > S_LEN - 1) gi = S_LEN - 1;   // clamped row never used
        float qv = wh[((size_t)b * S_LEN + gi) * (3 * DMODEL) + n * DHEAD + d];
        qrr[r][d] = qv + rrb[n * DHEAD + d];
        if (r < 16) qrw[r][d] = qv + rwb[n * DHEAD + d];
    }

    float m_i = -1e30f, l_i = 0.f;
    float o0 = 0.f, o1 = 0.f, o2 = 0.f, o3 = 0.f;
    const int i2 = t0 + ty;
    const float* qrw_row  = qrw[ty];
    const float* qrr_row0 = qrr[ty];
    const float* qrr_row1 = qrr[ty + 1];

    for (int u0 = 0; u0 < S_LEN; u0 += 16) {
        __syncthreads();   // also covers the q-staging on iteration 0
        for (int idx = tid; idx < 16 * 64; idx += 256) {
            int r = idx >> 6, d = idx & 63;
            size_t base = ((size_t)b * S_LEN + u0 + r) * (3 * DMODEL) + n * DHEAD + d;
            Ks[r][d] = wh[base + DMODEL];
            Vs[r][d] = wh[base + 2 * DMODEL];
        }
        __syncthreads();

        const int j2 = u0 + tx;
        float s;
        if (mask[b * S_LEN + j2] != 0) {
            s = -1e30f;
        } else {
            float ac = 0.f;
            #pragma unroll
            for (int d = 0; d < 64; d += 4) {
                float4 qv = *(const float4*)&qrw_row[d];
                float4 kv = *(const float4*)&Ks[tx][d];
                ac = fmaf(qv.x, kv.x, ac); ac = fmaf(qv.y, kv.y, ac);
                ac = fmaf(qv.z, kv.z, ac); ac = fmaf(qv.w, kv.w, ac);
            }
            float bd = 0.f;
            if (j2 <= i2) {
                const float* rrow = rk + (size_t)(S_LEN - 1 - i2 + j2) * DMODEL + n * DHEAD;
                #pragma unroll
                for (int d = 0; d < 64; d += 4) {
                    float4 qv = *(const float4*)&qrr_row0[d];
                    float4 rv = *(const float4*)&rrow[d];
                    bd = fmaf(qv.x, rv.x, bd); bd = fmaf(qv.y, rv.y, bd);
                    bd = fmaf(qv.z, rv.z, bd); bd = fmaf(qv.w, rv.w, bd);
                }
            } else if (j2 >= i2 + 2) {
                const float* rrow = rk + (size_t)(j2 - i2 - 2) * DMODEL + n * DHEAD;
                #pragma unroll
                for (int d = 0; d < 64; d += 4) {
                    float4 qv = *(const float4*)&qrr_row1[d];
                    float4 rv = *(const float4*)&rrow[d];
                    bd = fmaf(qv.x, rv.x, bd); bd = fmaf(qv.y, rv.y, bd);
                    bd = fmaf(qv.z, rv.z, bd); bd = fmaf(qv.w, rv.w, bd);
                }
            }
            s = (ac + bd) * 0.125f;   // 1/sqrt(64)
        }

        // online softmax over this 16-wide slab; row = 16 consecutive lanes
        float mrow = s;
        #pragma unroll
        for (int off = 8; off > 0; off >>= 1)
            mrow = fmaxf(mrow, __shfl_xor(mrow, off, 16));
        float m_new = fmaxf(m_i, mrow);
        float alpha = __expf(m_i - m_new);
        float p = __expf(s - m_new);
        float prow = p;
        #pragma unroll
        for (int off = 8; off > 0; off >>= 1)
            prow += __shfl_xor(prow, off, 16);
        l_i = l_i * alpha + prow;
        m_i = m_new;

        Ps[ty][tx] = p;   // row ty lanes are all in the same wave: no barrier

        o0 *= alpha; o1 *= alpha; o2 *= alpha; o3 *= alpha;
        #pragma unroll
        for (int jj = 0; jj < 16; ++jj) {
            float pv = Ps[ty][jj];
            float4 vv = *(const float4*)&Vs[jj][tx * 4];
            o0 = fmaf(pv, vv.x, o0); o1 = fmaf(pv, vv.y, o1);
            o2 = fmaf(pv, vv.z, o2); o3 = fmaf(pv, vv.w, o3);
        }
    }

    float inv_l = 1.0f / l_i;
    float4 outv = make_float4(o0 * inv_l, o1 * inv_l, o2 * inv_l, o3 * inv_l);
    *(float4*)(ctx + ((size_t)b * S_LEN + i2) * DMODEL + n * DHEAD + tx * 4) = outv;
}

// ---------------------------------------------------------------------------
// out = LayerNorm(x + attn_out) * gamma + beta ; one block per row of 1024
// ---------------------------------------------------------------------------
__global__ __launch_bounds__(256) void ln_kernel(const float* __restrict__ x,
                                                 const float* __restrict__ ao,
                                                 const float* __restrict__ gamma,
                                                 const float* __restrict__ beta,
                                                 float* __restrict__ out) {
    const int r = blockIdx.x;
    const int tid = threadIdx.x;
    const size_t base = (size_t)r * DMODEL + tid * 4;
    float4 xv = *(const float4*)(x + base);
    float4 av = *(const float4*)(ao + base);
    float v0 = xv.x + av.x, v1 = xv.y + av.y, v2 = xv.z + av.z, v3 = xv.w + av.w;

    float s = v0 + v1 + v2 + v3;
    #pragma unroll
    for (int off = 32; off > 0; off >>= 1) s += __shfl_xor(s, off, 64);
    __shared__ float red[4];
    __shared__ float red2[4];
    if ((tid & 63) == 0) red[tid >> 6] = s;
    __syncthreads();
    float mu = (red[0] + red[1] + red[2] + red[3]) * (1.0f / DMODEL);

    float d0 = v0 - mu, d1 = v1 - mu, d2 = v2 - mu, d3 = v3 - mu;
    float q = d0 * d0 + d1 * d1 + d2 * d2 + d3 * d3;
    #pragma unroll
    for (int off = 32; off > 0; off >>= 1) q += __shfl_xor(q, off, 64);
    if ((tid & 63) == 0) red2[tid >> 6] = q;
    __syncthreads();
    float var = (red2[0] + red2[1] + red2[2] + red2[3]) * (1.0f / DMODEL);
    float rstd = rsqrtf(var + 1e-5f);

    float4 g  = *(const float4*)(gamma + tid * 4);
    float4 be = *(const float4*)(beta + tid * 4);
    float4 o = make_float4(d0 * rstd * g.x + be.x,
                           d1 * rstd * g.y + be.y,
                           d2 * rstd * g.z + be.z,
                           d3 * rstd * g.w + be.w);
    *(float4*)(out + base) = o;
}

// ---------------------------------------------------------------------------
extern "C" void kernel_launch(void* const* d_in, const int* in_sizes, int n_in,
                              void* d_out, int out_size, void* d_ws, size_t ws_size,
                              hipStream_t stream) {
    const float* x    = (const float*)d_in[0];   // [2,2048,1024]
    const float* rpos = (const float*)d_in[1];   // [2048,1024]
    const float* rwb  = (const float*)d_in[2];   // [16,64]
    const float* rrb  = (const float*)d_in[3];   // [16,64]
    const int*   mask = (const int*)  d_in[4];   // [2,2048] (bool -> int)
    const float* Wqkv = (const float*)d_in[5];   // [1024,3072]
    const float* Wrel = (const float*)d_in[6];   // [1024,1024]
    const float* Wout = (const float*)d_in[7];   // [1024,1024]
    const float* gam  = (const float*)d_in[8];   // [1024]
    const float* bet  = (const float*)d_in[9];   // [1024]
    float* out = (float*)d_out;                  // [2,2048,1024]

    float* wh  = (float*)d_ws;                                  // [2,2048,3072]
    float* rk  = wh  + (size_t)NBATCH * S_LEN * 3 * DMODEL;     // [2048,1024]
    float* ctx = rk  + (size_t)S_LEN * DMODEL;                  // [2,2048,1024]
    float* ao  = ctx + (size_t)NBATCH * S_LEN * DMODEL;         // [2,2048,1024]

    dim3 blk(256);
    // 1. qkv projection
    gemm64<<<dim3((3 * DMODEL) / 64, (NBATCH * S_LEN) / 64), blk, 0, stream>>>(
        x, Wqkv, wh, NBATCH * S_LEN, 3 * DMODEL, DMODEL);
    // 2. relative-position projection
    gemm64<<<dim3(DMODEL / 64, S_LEN / 64), blk, 0, stream>>>(
        rpos, Wrel, rk, S_LEN, DMODEL, DMODEL);
    // 3. fused attention (rel-shift + mask + softmax + PV)
    attn_kernel<<<dim3(S_LEN / 16, NBATCH * NHEAD), blk, 0, stream>>>(
        wh, rk, rwb, rrb, mask, ctx);
    // 4. output projection
    gemm64<<<dim3(DMODEL / 64, (NBATCH * S_LEN) / 64), blk, 0, stream>>>(
        ctx, Wout, ao, NBATCH * S_LEN, DMODEL, DMODEL);
    // 5. residual + layernorm
    ln_kernel<<<dim3(NBATCH * S_LEN), blk, 0, stream>>>(x, ao, gam, bet, out);
}

// Round 2
// 1092.436 us; speedup vs baseline: 4.0434x; 4.0434x over previous
//
#include <hip/hip_runtime.h>
#include <hip/hip_bf16.h>
#include <math.h>

#define S_LEN 2048
#define NHEAD 16
#define DHEAD 64
#define DMODEL 1024
#define NBATCH 2

typedef __attribute__((ext_vector_type(8))) short bf16x8;
typedef __attribute__((ext_vector_type(4))) short short4v;
typedef __attribute__((ext_vector_type(4))) float f32x4;

__device__ __forceinline__ short f2bs(float x) {
    __hip_bfloat16 h = __float2bfloat16(x);
    return __builtin_bit_cast(short, h);
}

// ---------------------------------------------------------------------------
// Generic fp32 GEMM: C[M,N] = A[M,K] @ B[K,N], row-major, dims % 64 == 0.
// ---------------------------------------------------------------------------
__global__ __launch_bounds__(256) void gemm64(const float* __restrict__ A,
                                              const float* __restrict__ B,
                                              float* __restrict__ C,
                                              int M, int N, int K) {
    __shared__ float As[16][68];
    __shared__ float Bs[16][68];
    const int tid = threadIdx.x;
    const int row = tid >> 4;
    const int col = tid & 15;
    const int bm = blockIdx.y * 64;
    const int bn = blockIdx.x * 64;

    float acc[4][4] = {};

    for (int k0 = 0; k0 < K; k0 += 16) {
        {
            int a_idx = tid * 4;
            int ar = a_idx >> 4;
            int ak = a_idx & 15;
            float4 av = *(const float4*)(A + (size_t)(bm + ar) * K + k0 + ak);
            As[ak + 0][ar] = av.x;
            As[ak + 1][ar] = av.y;
            As[ak + 2][ar] = av.z;
            As[ak + 3][ar] = av.w;
        }
        {
            int b_idx = tid * 4;
            int bk = b_idx >> 6;
            int bnn = b_idx & 63;
            float4 bv = *(const float4*)(B + (size_t)(k0 + bk) * N + bn + bnn);
            *(float4*)&Bs[bk][bnn] = bv;
        }
        __syncthreads();
        #pragma unroll
        for (int k = 0; k < 16; ++k) {
            float4 a = *(const float4*)&As[k][row * 4];
            float4 b = *(const float4*)&Bs[k][col * 4];
            float af[4] = {a.x, a.y, a.z, a.w};
            float bf[4] = {b.x, b.y, b.z, b.w};
            #pragma unroll
            for (int i = 0; i < 4; ++i)
                #pragma unroll
                for (int j = 0; j < 4; ++j)
                    acc[i][j] = fmaf(af[i], bf[j], acc[i][j]);
        }
        __syncthreads();
    }
    #pragma unroll
    for (int i = 0; i < 4; ++i) {
        float4 v = make_float4(acc[i][0], acc[i][1], acc[i][2], acc[i][3]);
        *(float4*)(C + (size_t)(bm + row * 4 + i) * N + bn + col * 4) = v;
    }
}

// ---------------------------------------------------------------------------
// Repack wh (fp32 [B,S,3*1024]) into bf16 head-major tensors:
//   qrw_b/qrr_b/kb : [BH][S][64]   (q gets +rwb / +rrb bias pre-added)
//   vbT            : [BH][64][S]   (transposed for PV B-operand loads)
// ---------------------------------------------------------------------------
__global__ __launch_bounds__(256) void prep_qkv(
    const float* __restrict__ wh,
    const float* __restrict__ rwb, const float* __restrict__ rrb,
    short* __restrict__ qrw_b, short* __restrict__ qrr_b,
    short* __restrict__ kb, short* __restrict__ vbT)
{
    const int bs = blockIdx.x;            // b*S + s
    const int b = bs >> 11, s = bs & 2047;
    const int e0 = threadIdx.x * 4;       // [0,1024)
    const int h = e0 >> 6, d = e0 & 63;
    const int bh = b * NHEAD + h;
    const float* base = wh + (size_t)bs * 3 * DMODEL + e0;
    float4 q = *(const float4*)(base);
    float4 k = *(const float4*)(base + DMODEL);
    float4 v = *(const float4*)(base + 2 * DMODEL);
    float4 bw = *(const float4*)(rwb + e0);
    float4 br = *(const float4*)(rrb + e0);
    const size_t o = ((size_t)bh * S_LEN + s) * 64 + d;
    short4v t;
    t[0] = f2bs(q.x + bw.x); t[1] = f2bs(q.y + bw.y);
    t[2] = f2bs(q.z + bw.z); t[3] = f2bs(q.w + bw.w);
    *(short4v*)(qrw_b + o) = t;
    t[0] = f2bs(q.x + br.x); t[1] = f2bs(q.y + br.y);
    t[2] = f2bs(q.z + br.z); t[3] = f2bs(q.w + br.w);
    *(short4v*)(qrr_b + o) = t;
    t[0] = f2bs(k.x); t[1] = f2bs(k.y); t[2] = f2bs(k.z); t[3] = f2bs(k.w);
    *(short4v*)(kb + o) = t;
    const size_t vo = ((size_t)bh * 64 + d) * S_LEN + s;
    vbT[vo + 0 * S_LEN] = f2bs(v.x);
    vbT[vo + 1 * S_LEN] = f2bs(v.y);
    vbT[vo + 2 * S_LEN] = f2bs(v.z);
    vbT[vo + 3 * S_LEN] = f2bs(v.w);
}

// rk fp32 [S, 1024] -> rkb bf16 [NHEAD][S][64]
__global__ __launch_bounds__(256) void prep_rk(const float* __restrict__ rk,
                                               short* __restrict__ rkb) {
    const int l = blockIdx.x;
    const int e0 = threadIdx.x * 4;
    const int h = e0 >> 6, d = e0 & 63;
    float4 v = *(const float4*)(rk + (size_t)l * DMODEL + e0);
    const size_t o = ((size_t)h * S_LEN + l) * 64 + d;
    short4v t;
    t[0] = f2bs(v.x); t[1] = f2bs(v.y); t[2] = f2bs(v.z); t[3] = f2bs(v.w);
    *(short4v*)(rkb + o) = t;
}

// ---------------------------------------------------------------------------
// MFMA bf16 flash attention with analytic rel-shift.
// Grid: (S/64, B*NHEAD), 256 threads = 4 waves; wave w owns 16 q-rows.
// Per K-step (64 keys): ac = Qrw.K^T (8 MFMA); bd via G1/G2 16x80 GEMMs on
// diagonal index u = dj-di+15; source-side region merge; intra-quad shuffle
// extraction; fp32 online softmax; P->LDS->A-frag; O += P.V (8 MFMA).
// ---------------------------------------------------------------------------
__global__ __launch_bounds__(256) void flash_attn(
    const short* __restrict__ qrw_b, const short* __restrict__ qrr_b,
    const short* __restrict__ kb, const short* __restrict__ vbT,
    const short* __restrict__ rkb, const int* __restrict__ mask,
    float* __restrict__ ctx)
{
    const int lane = threadIdx.x & 63;
    const int w    = threadIdx.x >> 6;
    const int quad = lane >> 4;
    const int col  = lane & 15;
    const int bh   = blockIdx.y;
    const int b    = bh >> 4;
    const int n    = bh & 15;
    const int iw0  = blockIdx.x * 64 + w * 16;

    __shared__ short PT[4][64][20];   // per-wave P^T tile, bf16, padded

    const size_t headQ = (size_t)bh * S_LEN * 64;
    const size_t headR = (size_t)n  * S_LEN * 64;

    // A-fragments: lane holds A[m=col][k=quad*8+j (+32*kc)]
    bf16x8 a_rw[2], a_rr0[2], a_rr1[2];
    {
        const int r0 = iw0 + col;
        const int r1 = (r0 + 1 < S_LEN) ? (r0 + 1) : (S_LEN - 1);
        #pragma unroll
        for (int kc = 0; kc < 2; ++kc) {
            const int doff = kc * 32 + quad * 8;
            a_rw[kc]  = *(const bf16x8*)(qrw_b + headQ + (size_t)r0 * 64 + doff);
            a_rr0[kc] = *(const bf16x8*)(qrr_b + headQ + (size_t)r0 * 64 + doff);
            a_rr1[kc] = *(const bf16x8*)(qrr_b + headQ + (size_t)r1 * 64 + doff);
        }
    }

    f32x4 O[4];
    float m_i[4], l_i[4];
    #pragma unroll
    for (int r = 0; r < 4; ++r) { m_i[r] = -1e30f; l_i[r] = 0.f; }
    #pragma unroll
    for (int dt = 0; dt < 4; ++dt) O[dt] = (f32x4){0.f, 0.f, 0.f, 0.f};

    for (int u0 = 0; u0 < S_LEN; u0 += 64) {
        // -------- ac: C[di][dj] = sum_d Qrw[iw0+di][d] K[u0+dj][d] --------
        f32x4 sc[4];
        #pragma unroll
        for (int nt = 0; nt < 4; ++nt) {
            f32x4 c = (f32x4){0.f, 0.f, 0.f, 0.f};
            const short* kbase = kb + headQ + (size_t)(u0 + nt * 16 + col) * 64 + quad * 8;
            c = __builtin_amdgcn_mfma_f32_16x16x32_bf16(a_rw[0], *(const bf16x8*)(kbase), c, 0, 0, 0);
            c = __builtin_amdgcn_mfma_f32_16x16x32_bf16(a_rw[1], *(const bf16x8*)(kbase + 32), c, 0, 0, 0);
            sc[nt] = c;
        }

        // -------- bd: G1/G2 over diagonal index u = dj-di+15 in [0,80) ----
        const int delta = iw0 - u0;           // wave-uniform, multiple of 16
        const bool need1 = (delta >= -15);    // some j <= i
        const bool need2 = (delta <= 61);     // some j >= i+2
        f32x4 g1[5], g2[5];
        #pragma unroll
        for (int g = 0; g < 5; ++g) {
            g1[g] = (f32x4){0.f, 0.f, 0.f, 0.f};
            g2[g] = (f32x4){0.f, 0.f, 0.f, 0.f};
        }
        if (need1) {
            const int c1 = S_LEN - 16 - delta;    // rk row = c1 + u
            #pragma unroll
            for (int g = 0; g < 5; ++g) {
                int row = c1 + g * 16 + col;
                row = row < 0 ? 0 : (row > S_LEN - 1 ? S_LEN - 1 : row);
                const short* rb = rkb + headR + (size_t)row * 64 + quad * 8;
                f32x4 c = g1[g];
                c = __builtin_amdgcn_mfma_f32_16x16x32_bf16(a_rr0[0], *(const bf16x8*)(rb), c, 0, 0, 0);
                c = __builtin_amdgcn_mfma_f32_16x16x32_bf16(a_rr0[1], *(const bf16x8*)(rb + 32), c, 0, 0, 0);
                g1[g] = c;
            }
        }
        if (need2) {
            const int c2 = -delta - 17;           // rk row = c2 + u
            #pragma unroll
            for (int g = 0; g < 5; ++g) {
                int row = c2 + g * 16 + col;
                row = row < 0 ? 0 : (row > S_LEN - 1 ? S_LEN - 1 : row);
                const short* rb = rkb + headR + (size_t)row * 64 + quad * 8;
                f32x4 c = g2[g];
                c = __builtin_amdgcn_mfma_f32_16x16x32_bf16(a_rr1[0], *(const bf16x8*)(rb), c, 0, 0, 0);
                c = __builtin_amdgcn_mfma_f32_16x16x32_bf16(a_rr1[1], *(const bf16x8*)(rb + 32), c, 0, 0, 0);
                g2[g] = c;
            }
        }
        // source-side region merge: u<=15+delta -> G1; u==16+delta -> 0; else G2
        const int lim1 = 15 + delta;
        #pragma unroll
        for (int g = 0; g < 5; ++g) {
            const int u = g * 16 + col;
            #pragma unroll
            for (int r = 0; r < 4; ++r)
                g1[g][r] = (u <= lim1) ? g1[g][r] : ((u == lim1 + 1) ? 0.f : g2[g][r]);
        }
        // diagonal extraction (intra-quad shuffle) + ac + scale + mask
        #pragma unroll
        for (int nt = 0; nt < 4; ++nt) {
            const int mv = mask[b * S_LEN + u0 + nt * 16 + col];
            #pragma unroll
            for (int r = 0; r < 4; ++r) {
                const int uo = col + 15 - quad * 4 - r;     // in [0,30]
                const int src = (quad << 4) | (uo & 15);
                float blo = __shfl(g1[nt][r], src, 64);
                float bhi = __shfl(g1[nt + 1][r], src, 64);
                float bd = (uo < 16) ? blo : bhi;
                float s = (sc[nt][r] + bd) * 0.125f;
                sc[nt][r] = mv ? -1e30f : s;
            }
        }

        // -------- online softmax (row di = quad*4+r across 16 lanes) ------
        float alpha[4], rs[4];
        #pragma unroll
        for (int r = 0; r < 4; ++r) {
            float m0 = fmaxf(fmaxf(sc[0][r], sc[1][r]), fmaxf(sc[2][r], sc[3][r]));
            #pragma unroll
            for (int off = 1; off < 16; off <<= 1)
                m0 = fmaxf(m0, __shfl_xor(m0, off, 64));
            float mn = fmaxf(m_i[r], m0);
            alpha[r] = __expf(m_i[r] - mn);
            m_i[r] = mn;
            rs[r] = 0.f;
        }
        #pragma unroll
        for (int nt = 0; nt < 4; ++nt) {
            #pragma unroll
            for (int r = 0; r < 4; ++r) {
                float p = __expf(sc[nt][r] - m_i[r]);
                sc[nt][r] = p;
                rs[r] += p;
            }
        }
        #pragma unroll
        for (int r = 0; r < 4; ++r) {
            #pragma unroll
            for (int off = 1; off < 16; off <<= 1)
                rs[r] += __shfl_xor(rs[r], off, 64);
            l_i[r] = l_i[r] * alpha[r] + rs[r];
        }
        #pragma unroll
        for (int dt = 0; dt < 4; ++dt) {
            O[dt][0] *= alpha[0]; O[dt][1] *= alpha[1];
            O[dt][2] *= alpha[2]; O[dt][3] *= alpha[3];
        }

        // -------- P: C-layout -> LDS (transposed bf16) -> A-frags ---------
        #pragma unroll
        for (int nt = 0; nt < 4; ++nt) {
            short4v pb;
            pb[0] = f2bs(sc[nt][0]); pb[1] = f2bs(sc[nt][1]);
            pb[2] = f2bs(sc[nt][2]); pb[3] = f2bs(sc[nt][3]);
            *(short4v*)&PT[w][nt * 16 + col][quad * 4] = pb;   // PT[dj][di]
        }
        bf16x8 pa[2];
        #pragma unroll
        for (int kc = 0; kc < 2; ++kc) {
            bf16x8 t;
            #pragma unroll
            for (int jj = 0; jj < 8; ++jj)
                t[jj] = PT[w][kc * 32 + quad * 8 + jj][col];   // A[m=col][k]
            pa[kc] = t;
        }

        // -------- O += P.V ------------------------------------------------
        #pragma unroll
        for (int dt = 0; dt < 4; ++dt) {
            const short* vb = vbT + ((size_t)bh * 64 + dt * 16 + col) * S_LEN + u0 + quad * 8;
            f32x4 c = O[dt];
            c = __builtin_amdgcn_mfma_f32_16x16x32_bf16(pa[0], *(const bf16x8*)(vb), c, 0, 0, 0);
            c = __builtin_amdgcn_mfma_f32_16x16x32_bf16(pa[1], *(const bf16x8*)(vb + 32), c, 0, 0, 0);
            O[dt] = c;
        }
    }

    float inv[4];
    #pragma unroll
    for (int r = 0; r < 4; ++r) inv[r] = 1.f / l_i[r];
    #pragma unroll
    for (int dt = 0; dt < 4; ++dt)
        #pragma unroll
        for (int r = 0; r < 4; ++r) {
            const int i = iw0 + quad * 4 + r;
            ctx[((size_t)b * S_LEN + i) * DMODEL + n * 64 + dt * 16 + col] = O[dt][r] * inv[r];
        }
}

// ---------------------------------------------------------------------------
// out = LayerNorm(x + attn_out)
// ---------------------------------------------------------------------------
__global__ __launch_bounds__(256) void ln_kernel(const float* __restrict__ x,
                                                 const float* __restrict__ ao,
                                                 const float* __restrict__ gamma,
                                                 const float* __restrict__ beta,
                                                 float* __restrict__ out) {
    const int r = blockIdx.x;
    const int tid = threadIdx.x;
    const size_t base = (size_t)r * DMODEL + tid * 4;
    float4 xv = *(const float4*)(x + base);
    float4 av = *(const float4*)(ao + base);
    float v0 = xv.x + av.x, v1 = xv.y + av.y, v2 = xv.z + av.z, v3 = xv.w + av.w;

    float s = v0 + v1 + v2 + v3;
    #pragma unroll
    for (int off = 32; off > 0; off >>= 1) s += __shfl_xor(s, off, 64);
    __shared__ float red[4];
    __shared__ float red2[4];
    if ((tid & 63) == 0) red[tid >> 6] = s;
    __syncthreads();
    float mu = (red[0] + red[1] + red[2] + red[3]) * (1.0f / DMODEL);

    float d0 = v0 - mu, d1 = v1 - mu, d2 = v2 - mu, d3 = v3 - mu;
    float q = d0 * d0 + d1 * d1 + d2 * d2 + d3 * d3;
    #pragma unroll
    for (int off = 32; off > 0; off >>= 1) q += __shfl_xor(q, off, 64);
    if ((tid & 63) == 0) red2[tid >> 6] = q;
    __syncthreads();
    float var = (red2[0] + red2[1] + red2[2] + red2[3]) * (1.0f / DMODEL);
    float rstd = rsqrtf(var + 1e-5f);

    float4 g  = *(const float4*)(gamma + tid * 4);
    float4 be = *(const float4*)(beta + tid * 4);
    float4 o = make_float4(d0 * rstd * g.x + be.x,
                           d1 * rstd * g.y + be.y,
                           d2 * rstd * g.z + be.z,
                           d3 * rstd * g.w + be.w);
    *(float4*)(out + base) = o;
}

// ---------------------------------------------------------------------------
extern "C" void kernel_launch(void* const* d_in, const int* in_sizes, int n_in,
                              void* d_out, int out_size, void* d_ws, size_t ws_size,
                              hipStream_t stream) {
    const float* x    = (const float*)d_in[0];
    const float* rpos = (const float*)d_in[1];
    const float* rwb  = (const float*)d_in[2];
    const float* rrb  = (const float*)d_in[3];
    const int*   mask = (const int*)  d_in[4];
    const float* Wqkv = (const float*)d_in[5];
    const float* Wrel = (const float*)d_in[6];
    const float* Wout = (const float*)d_in[7];
    const float* gam  = (const float*)d_in[8];
    const float* bet  = (const float*)d_in[9];
    float* out = (float*)d_out;

    // workspace layout (ctx/ao alias the wh region, dead after prep):
    float* wh  = (float*)d_ws;                      // 12,582,912 f
    float* ctx = wh;                                //  4,194,304 f (alias)
    float* ao  = wh + 4194304;                      //  4,194,304 f (alias)
    float* rk  = wh + 12582912;                     //  2,097,152 f
    short* qrw_b = (short*)(rk + 2097152);          //  4,194,304 s
    short* qrr_b = qrw_b + 4194304;
    short* kb    = qrr_b + 4194304;
    short* vbT   = kb + 4194304;
    short* rkb   = vbT + 4194304;                   //  2,097,152 s
    // total: 96,468,992 bytes

    dim3 blk(256);
    gemm64<<<dim3((3 * DMODEL) / 64, (NBATCH * S_LEN) / 64), blk, 0, stream>>>(
        x, Wqkv, wh, NBATCH * S_LEN, 3 * DMODEL, DMODEL);
    gemm64<<<dim3(DMODEL / 64, S_LEN / 64), blk, 0, stream>>>(
        rpos, Wrel, rk, S_LEN, DMODEL, DMODEL);
    prep_qkv<<<dim3(NBATCH * S_LEN), blk, 0, stream>>>(wh, rwb, rrb, qrw_b, qrr_b, kb, vbT);
    prep_rk<<<dim3(S_LEN), blk, 0, stream>>>(rk, rkb);
    flash_attn<<<dim3(S_LEN / 64, NBATCH * NHEAD), blk, 0, stream>>>(
        qrw_b, qrr_b, kb, vbT, rkb, mask, ctx);
    gemm64<<<dim3(DMODEL / 64, (NBATCH * S_LEN) / 64), blk, 0, stream>>>(
        ctx, Wout, ao, NBATCH * S_LEN, DMODEL, DMODEL);
    ln_kernel<<<dim3(NBATCH * S_LEN), blk, 0, stream>>>(x, ao, gam, bet, out);
}

// Round 3
// 601.114 us; speedup vs baseline: 7.3483x; 1.8174x over previous
//
#include <hip/hip_runtime.h>
#include <hip/hip_bf16.h>
#include <math.h>

#define S_LEN 2048
#define NHEAD 16
#define DHEAD 64
#define DMODEL 1024
#define NBATCH 2

typedef unsigned short u16;
typedef __attribute__((ext_vector_type(8))) short bf16x8;
typedef __attribute__((ext_vector_type(4))) short short4v;
typedef __attribute__((ext_vector_type(4))) float f32x4;

__device__ __forceinline__ short f2bs(float x) {
    __hip_bfloat16 h = __float2bfloat16(x);
    return __builtin_bit_cast(short, h);
}
__device__ __forceinline__ float bs2f(u16 u) {
    unsigned int x = ((unsigned int)u) << 16;
    return __builtin_bit_cast(float, x);
}

#define GL2LDS(g, l)                                                         \
    __builtin_amdgcn_global_load_lds(                                        \
        (const __attribute__((address_space(1))) void*)(g),                  \
        (__attribute__((address_space(3))) void*)(l), 16, 0, 0)

// ---------------------------------------------------------------------------
// fp32 -> bf16 flat cast. n must be divisible by 1024. grid = n/1024.
// ---------------------------------------------------------------------------
__global__ __launch_bounds__(256) void cast_f32_bf16(const float* __restrict__ in,
                                                     u16* __restrict__ out) {
    const int i = (blockIdx.x * 256 + threadIdx.x) * 4;
    float4 v = *(const float4*)(in + i);
    short4v t;
    t[0] = f2bs(v.x); t[1] = f2bs(v.y); t[2] = f2bs(v.z); t[3] = f2bs(v.w);
    *(short4v*)(out + i) = t;
}

// ---------------------------------------------------------------------------
// W [K][N] fp32 -> Wt [N][K] bf16 (transpose + cast), 64x64 LDS tile.
// grid = (N/64, K/64)
// ---------------------------------------------------------------------------
__global__ __launch_bounds__(256) void transp_cast(const float* __restrict__ W,
                                                   u16* __restrict__ Wt,
                                                   int K, int N) {
    __shared__ float t[64][65];
    const int k0 = blockIdx.y * 64, n0 = blockIdx.x * 64;
    const int r = threadIdx.x >> 4;
    const int c4 = (threadIdx.x & 15) * 4;
    #pragma unroll
    for (int it = 0; it < 4; ++it) {
        float4 v = *(const float4*)(W + (size_t)(k0 + it * 16 + r) * N + n0 + c4);
        t[c4 + 0][it * 16 + r] = v.x;
        t[c4 + 1][it * 16 + r] = v.y;
        t[c4 + 2][it * 16 + r] = v.z;
        t[c4 + 3][it * 16 + r] = v.w;
    }
    __syncthreads();
    #pragma unroll
    for (int it = 0; it < 4; ++it) {
        const int nn = it * 16 + r;
        short4v o;
        o[0] = f2bs(t[nn][c4 + 0]); o[1] = f2bs(t[nn][c4 + 1]);
        o[2] = f2bs(t[nn][c4 + 2]); o[3] = f2bs(t[nn][c4 + 3]);
        *(short4v*)(Wt + (size_t)(n0 + nn) * K + k0 + c4) = o;
    }
}

// ---------------------------------------------------------------------------
// bf16 MFMA GEMM (m97 structure): C[M,N] = A[M,K] @ Bt[N,K]^T.
// 128x128 tile, BK=64, 4 waves (2x2 of 64x64), global_load_lds width-16,
// XOR-swizzled LDS (conflict-free ds_read_b128). Output fp32 or bf16.
// ---------------------------------------------------------------------------
__global__ __launch_bounds__(256, 2) void gemm_bf16(
    const u16* __restrict__ A, const u16* __restrict__ Bt,
    float* __restrict__ Cf, u16* __restrict__ Cb,
    int M, int N, int K)
{
    __shared__ u16 As[128 * 64];
    __shared__ u16 Bs[128 * 64];
    const int tid = threadIdx.x;
    const int lane = tid & 63;
    const int w = tid >> 6;
    const int quad = lane >> 4, col = lane & 15;
    const int bm = blockIdx.y * 128, bn = blockIdx.x * 128;
    const int wm = (w >> 1) * 64, wn = (w & 1) * 64;

    f32x4 acc[4][4];
    #pragma unroll
    for (int mt = 0; mt < 4; ++mt)
        #pragma unroll
        for (int nt = 0; nt < 4; ++nt) acc[mt][nt] = (f32x4){0.f, 0.f, 0.f, 0.f};

    for (int k0 = 0; k0 < K; k0 += 64) {
        #pragma unroll
        for (int it = 0; it < 4; ++it) {
            const int cb = it * 256 + w * 64;          // wave-uniform chunk base
            const int c = cb + lane;
            const int r = c >> 3;
            const int o = ((c & 7) ^ (r & 7)) * 8;     // XOR swizzle (ushorts)
            GL2LDS(A + (size_t)(bm + r) * K + k0 + o, As + (size_t)cb * 8);
            GL2LDS(Bt + (size_t)(bn + r) * K + k0 + o, Bs + (size_t)cb * 8);
        }
        __syncthreads();
        #pragma unroll
        for (int kc = 0; kc < 2; ++kc) {
            bf16x8 af[4], bfr[4];
            #pragma unroll
            for (int t = 0; t < 4; ++t) {
                const int am = wm + t * 16 + col;
                const int aj = kc * 4 + quad;
                af[t] = *(const bf16x8*)&As[(size_t)am * 64 + ((aj ^ (am & 7)) * 8)];
                const int bn2 = wn + t * 16 + col;
                bfr[t] = *(const bf16x8*)&Bs[(size_t)bn2 * 64 + ((aj ^ (bn2 & 7)) * 8)];
            }
            #pragma unroll
            for (int mt = 0; mt < 4; ++mt)
                #pragma unroll
                for (int nt = 0; nt < 4; ++nt)
                    acc[mt][nt] = __builtin_amdgcn_mfma_f32_16x16x32_bf16(
                        af[mt], bfr[nt], acc[mt][nt], 0, 0, 0);
        }
        __syncthreads();
    }

    if (Cb) {
        #pragma unroll
        for (int mt = 0; mt < 4; ++mt)
            #pragma unroll
            for (int nt = 0; nt < 4; ++nt)
                #pragma unroll
                for (int r = 0; r < 4; ++r) {
                    const int row = bm + wm + mt * 16 + quad * 4 + r;
                    const int cn = bn + wn + nt * 16 + col;
                    Cb[(size_t)row * N + cn] = (u16)f2bs(acc[mt][nt][r]);
                }
    } else {
        #pragma unroll
        for (int mt = 0; mt < 4; ++mt)
            #pragma unroll
            for (int nt = 0; nt < 4; ++nt)
                #pragma unroll
                for (int r = 0; r < 4; ++r) {
                    const int row = bm + wm + mt * 16 + quad * 4 + r;
                    const int cn = bn + wn + nt * 16 + col;
                    Cf[(size_t)row * N + cn] = acc[mt][nt][r];
                }
    }
}

// ---------------------------------------------------------------------------
// Repack wh_b (bf16 [B,S,3*1024]) into head-major bf16 tensors.
// ---------------------------------------------------------------------------
__global__ __launch_bounds__(256) void prep_qkv(
    const u16* __restrict__ wh,
    const float* __restrict__ rwb, const float* __restrict__ rrb,
    u16* __restrict__ qrw_b, u16* __restrict__ qrr_b,
    u16* __restrict__ kb, u16* __restrict__ vbT)
{
    const int bs = blockIdx.x;
    const int b = bs >> 11, s = bs & 2047;
    const int e0 = threadIdx.x * 4;
    const int h = e0 >> 6, d = e0 & 63;
    const int bh = b * NHEAD + h;
    const u16* base = wh + (size_t)bs * 3 * DMODEL + e0;
    short4v q = *(const short4v*)(base);
    short4v k = *(const short4v*)(base + DMODEL);
    short4v v = *(const short4v*)(base + 2 * DMODEL);
    float4 bw = *(const float4*)(rwb + e0);
    float4 br = *(const float4*)(rrb + e0);
    const size_t o = ((size_t)bh * S_LEN + s) * 64 + d;
    short4v t;
    t[0] = f2bs(bs2f((u16)q[0]) + bw.x); t[1] = f2bs(bs2f((u16)q[1]) + bw.y);
    t[2] = f2bs(bs2f((u16)q[2]) + bw.z); t[3] = f2bs(bs2f((u16)q[3]) + bw.w);
    *(short4v*)(qrw_b + o) = t;
    t[0] = f2bs(bs2f((u16)q[0]) + br.x); t[1] = f2bs(bs2f((u16)q[1]) + br.y);
    t[2] = f2bs(bs2f((u16)q[2]) + br.z); t[3] = f2bs(bs2f((u16)q[3]) + br.w);
    *(short4v*)(qrr_b + o) = t;
    *(short4v*)(kb + o) = k;
    const size_t vo = ((size_t)bh * 64 + d) * S_LEN + s;
    vbT[vo + 0 * S_LEN] = (u16)v[0];
    vbT[vo + 1 * S_LEN] = (u16)v[1];
    vbT[vo + 2 * S_LEN] = (u16)v[2];
    vbT[vo + 3 * S_LEN] = (u16)v[3];
}

// rk_b bf16 [S,1024] -> rkb bf16 [NHEAD][S][64]
__global__ __launch_bounds__(256) void prep_rk(const u16* __restrict__ rk_b,
                                               u16* __restrict__ rkb) {
    const int l = blockIdx.x;
    const int e0 = threadIdx.x * 4;
    const int h = e0 >> 6, d = e0 & 63;
    short4v v = *(const short4v*)(rk_b + (size_t)l * DMODEL + e0);
    *(short4v*)(rkb + ((size_t)h * S_LEN + l) * 64 + d) = v;
}

// ---------------------------------------------------------------------------
// MFMA bf16 flash attention, analytic rel-shift, software-pipelined:
// all global loads of a step issued at step top (one latency exposure).
// ---------------------------------------------------------------------------
__global__ __launch_bounds__(256, 2) void flash_attn(
    const u16* __restrict__ qrw_b, const u16* __restrict__ qrr_b,
    const u16* __restrict__ kb, const u16* __restrict__ vbT,
    const u16* __restrict__ rkb, const int* __restrict__ mask,
    u16* __restrict__ ctxb)
{
    const int lane = threadIdx.x & 63;
    const int w    = threadIdx.x >> 6;
    const int quad = lane >> 4;
    const int col  = lane & 15;
    const int bh   = blockIdx.y;
    const int b    = bh >> 4;
    const int n    = bh & 15;
    const int iw0  = blockIdx.x * 64 + w * 16;

    __shared__ u16 Pr[4][16][72];   // P row-major per wave; 144B row stride

    const size_t headQ = (size_t)bh * S_LEN * 64;
    const size_t headR = (size_t)n  * S_LEN * 64;

    bf16x8 a_rw[2], a_rr0[2], a_rr1[2];
    {
        const int r0 = iw0 + col;
        const int r1 = (r0 + 1 < S_LEN) ? (r0 + 1) : (S_LEN - 1);
        #pragma unroll
        for (int kc = 0; kc < 2; ++kc) {
            const int doff = kc * 32 + quad * 8;
            a_rw[kc]  = *(const bf16x8*)(qrw_b + headQ + (size_t)r0 * 64 + doff);
            a_rr0[kc] = *(const bf16x8*)(qrr_b + headQ + (size_t)r0 * 64 + doff);
            a_rr1[kc] = *(const bf16x8*)(qrr_b + headQ + (size_t)r1 * 64 + doff);
        }
    }

    f32x4 O[4];
    float m_i[4], l_i[4];
    #pragma unroll
    for (int r = 0; r < 4; ++r) { m_i[r] = -1e30f; l_i[r] = 0.f; }
    #pragma unroll
    for (int dt = 0; dt < 4; ++dt) O[dt] = (f32x4){0.f, 0.f, 0.f, 0.f};

    for (int u0 = 0; u0 < S_LEN; u0 += 64) {
        const int delta = iw0 - u0;          // wave-uniform, multiple of 16
        const bool need1 = (delta >= 0);
        const bool need2 = (delta <= 48);

        // ---------------- hoisted loads: all in flight together -----------
        bf16x8 kf[4][2];
        #pragma unroll
        for (int nt = 0; nt < 4; ++nt) {
            const u16* kbase = kb + headQ + (size_t)(u0 + nt * 16 + col) * 64 + quad * 8;
            kf[nt][0] = *(const bf16x8*)(kbase);
            kf[nt][1] = *(const bf16x8*)(kbase + 32);
        }
        bf16x8 r1f[5][2], r2f[5][2];
        if (need1) {
            const int c1 = S_LEN - 16 - delta;
            #pragma unroll
            for (int g = 0; g < 5; ++g) {
                int row = c1 + g * 16 + col;
                row = row < 0 ? 0 : (row > S_LEN - 1 ? S_LEN - 1 : row);
                const u16* rb = rkb + headR + (size_t)row * 64 + quad * 8;
                r1f[g][0] = *(const bf16x8*)(rb);
                r1f[g][1] = *(const bf16x8*)(rb + 32);
            }
        }
        if (need2) {
            const int c2 = -delta - 17;
            #pragma unroll
            for (int g = 0; g < 5; ++g) {
                int row = c2 + g * 16 + col;
                row = row < 0 ? 0 : (row > S_LEN - 1 ? S_LEN - 1 : row);
                const u16* rb = rkb + headR + (size_t)row * 64 + quad * 8;
                r2f[g][0] = *(const bf16x8*)(rb);
                r2f[g][1] = *(const bf16x8*)(rb + 32);
            }
        }
        int mv[4];
        #pragma unroll
        for (int nt = 0; nt < 4; ++nt)
            mv[nt] = mask[b * S_LEN + u0 + nt * 16 + col];
        bf16x8 vf[4][2];
        #pragma unroll
        for (int dt = 0; dt < 4; ++dt) {
            const u16* vb = vbT + ((size_t)bh * 64 + dt * 16 + col) * S_LEN + u0 + quad * 8;
            vf[dt][0] = *(const bf16x8*)(vb);
            vf[dt][1] = *(const bf16x8*)(vb + 32);
        }

        // ---------------- ac ----------------------------------------------
        f32x4 sc[4];
        #pragma unroll
        for (int nt = 0; nt < 4; ++nt) {
            f32x4 c = (f32x4){0.f, 0.f, 0.f, 0.f};
            c = __builtin_amdgcn_mfma_f32_16x16x32_bf16(a_rw[0], kf[nt][0], c, 0, 0, 0);
            c = __builtin_amdgcn_mfma_f32_16x16x32_bf16(a_rw[1], kf[nt][1], c, 0, 0, 0);
            sc[nt] = c;
        }

        // ---------------- bd: diagonal GEMMs -------------------------------
        f32x4 g1[5], g2[5];
        #pragma unroll
        for (int g = 0; g < 5; ++g) {
            g1[g] = (f32x4){0.f, 0.f, 0.f, 0.f};
            g2[g] = (f32x4){0.f, 0.f, 0.f, 0.f};
        }
        if (need1) {
            #pragma unroll
            for (int g = 0; g < 5; ++g) {
                f32x4 c = g1[g];
                c = __builtin_amdgcn_mfma_f32_16x16x32_bf16(a_rr0[0], r1f[g][0], c, 0, 0, 0);
                c = __builtin_amdgcn_mfma_f32_16x16x32_bf16(a_rr0[1], r1f[g][1], c, 0, 0, 0);
                g1[g] = c;
            }
        }
        if (need2) {
            #pragma unroll
            for (int g = 0; g < 5; ++g) {
                f32x4 c = g2[g];
                c = __builtin_amdgcn_mfma_f32_16x16x32_bf16(a_rr1[0], r2f[g][0], c, 0, 0, 0);
                c = __builtin_amdgcn_mfma_f32_16x16x32_bf16(a_rr1[1], r2f[g][1], c, 0, 0, 0);
                g2[g] = c;
            }
        }
        // source-side region merge: u<=15+delta -> G1; u==16+delta -> 0; else G2
        const int lim1 = 15 + delta;
        #pragma unroll
        for (int g = 0; g < 5; ++g) {
            const int u = g * 16 + col;
            #pragma unroll
            for (int r = 0; r < 4; ++r)
                g1[g][r] = (u <= lim1) ? g1[g][r] : ((u == lim1 + 1) ? 0.f : g2[g][r]);
        }
        // diagonal extraction + ac + scale + mask
        #pragma unroll
        for (int nt = 0; nt < 4; ++nt) {
            #pragma unroll
            for (int r = 0; r < 4; ++r) {
                const int uo = col + 15 - quad * 4 - r;
                const int src = (quad << 4) | (uo & 15);
                float blo = __shfl(g1[nt][r], src, 64);
                float bhi = __shfl(g1[nt + 1][r], src, 64);
                float bd = (uo < 16) ? blo : bhi;
                float s = (sc[nt][r] + bd) * 0.125f;
                sc[nt][r] = mv[nt] ? -1e30f : s;
            }
        }

        // ---------------- online softmax -----------------------------------
        float alpha[4], rs[4];
        #pragma unroll
        for (int r = 0; r < 4; ++r) {
            float m0 = fmaxf(fmaxf(sc[0][r], sc[1][r]), fmaxf(sc[2][r], sc[3][r]));
            #pragma unroll
            for (int off = 1; off < 16; off <<= 1)
                m0 = fmaxf(m0, __shfl_xor(m0, off, 64));
            float mn = fmaxf(m_i[r], m0);
            alpha[r] = __expf(m_i[r] - mn);
            m_i[r] = mn;
            rs[r] = 0.f;
        }
        #pragma unroll
        for (int nt = 0; nt < 4; ++nt) {
            #pragma unroll
            for (int r = 0; r < 4; ++r) {
                float p = __expf(sc[nt][r] - m_i[r]);
                sc[nt][r] = p;
                rs[r] += p;
            }
        }
        #pragma unroll
        for (int r = 0; r < 4; ++r) {
            #pragma unroll
            for (int off = 1; off < 16; off <<= 1)
                rs[r] += __shfl_xor(rs[r], off, 64);
            l_i[r] = l_i[r] * alpha[r] + rs[r];
        }
        #pragma unroll
        for (int dt = 0; dt < 4; ++dt) {
            O[dt][0] *= alpha[0]; O[dt][1] *= alpha[1];
            O[dt][2] *= alpha[2]; O[dt][3] *= alpha[3];
        }

        // ---------------- P: C-layout -> LDS row-major -> A-frags ----------
        #pragma unroll
        for (int nt = 0; nt < 4; ++nt)
            #pragma unroll
            for (int r = 0; r < 4; ++r)
                Pr[w][quad * 4 + r][nt * 16 + col] = (u16)f2bs(sc[nt][r]);
        bf16x8 pa[2];
        pa[0] = *(const bf16x8*)&Pr[w][col][quad * 8];
        pa[1] = *(const bf16x8*)&Pr[w][col][32 + quad * 8];

        // ---------------- O += P.V -----------------------------------------
        #pragma unroll
        for (int dt = 0; dt < 4; ++dt) {
            f32x4 c = O[dt];
            c = __builtin_amdgcn_mfma_f32_16x16x32_bf16(pa[0], vf[dt][0], c, 0, 0, 0);
            c = __builtin_amdgcn_mfma_f32_16x16x32_bf16(pa[1], vf[dt][1], c, 0, 0, 0);
            O[dt] = c;
        }
    }

    float inv[4];
    #pragma unroll
    for (int r = 0; r < 4; ++r) inv[r] = 1.f / l_i[r];
    #pragma unroll
    for (int dt = 0; dt < 4; ++dt)
        #pragma unroll
        for (int r = 0; r < 4; ++r) {
            const int i = iw0 + quad * 4 + r;
            ctxb[((size_t)b * S_LEN + i) * DMODEL + n * 64 + dt * 16 + col] =
                (u16)f2bs(O[dt][r] * inv[r]);
        }
}

// ---------------------------------------------------------------------------
// out = LayerNorm(x + attn_out)
// ---------------------------------------------------------------------------
__global__ __launch_bounds__(256) void ln_kernel(const float* __restrict__ x,
                                                 const float* __restrict__ ao,
                                                 const float* __restrict__ gamma,
                                                 const float* __restrict__ beta,
                                                 float* __restrict__ out) {
    const int r = blockIdx.x;
    const int tid = threadIdx.x;
    const size_t base = (size_t)r * DMODEL + tid * 4;
    float4 xv = *(const float4*)(x + base);
    float4 av = *(const float4*)(ao + base);
    float v0 = xv.x + av.x, v1 = xv.y + av.y, v2 = xv.z + av.z, v3 = xv.w + av.w;

    float s = v0 + v1 + v2 + v3;
    #pragma unroll
    for (int off = 32; off > 0; off >>= 1) s += __shfl_xor(s, off, 64);
    __shared__ float red[4];
    __shared__ float red2[4];
    if ((tid & 63) == 0) red[tid >> 6] = s;
    __syncthreads();
    float mu = (red[0] + red[1] + red[2] + red[3]) * (1.0f / DMODEL);

    float d0 = v0 - mu, d1 = v1 - mu, d2 = v2 - mu, d3 = v3 - mu;
    float q = d0 * d0 + d1 * d1 + d2 * d2 + d3 * d3;
    #pragma unroll
    for (int off = 32; off > 0; off >>= 1) q += __shfl_xor(q, off, 64);
    if ((tid & 63) == 0) red2[tid >> 6] = q;
    __syncthreads();
    float var = (red2[0] + red2[1] + red2[2] + red2[3]) * (1.0f / DMODEL);
    float rstd = rsqrtf(var + 1e-5f);

    float4 g  = *(const float4*)(gamma + tid * 4);
    float4 be = *(const float4*)(beta + tid * 4);
    float4 o = make_float4(d0 * rstd * g.x + be.x,
                           d1 * rstd * g.y + be.y,
                           d2 * rstd * g.z + be.z,
                           d3 * rstd * g.w + be.w);
    *(float4*)(out + base) = o;
}

// ---------------------------------------------------------------------------
extern "C" void kernel_launch(void* const* d_in, const int* in_sizes, int n_in,
                              void* d_out, int out_size, void* d_ws, size_t ws_size,
                              hipStream_t stream) {
    const float* x    = (const float*)d_in[0];
    const float* rpos = (const float*)d_in[1];
    const float* rwb  = (const float*)d_in[2];
    const float* rrb  = (const float*)d_in[3];
    const int*   mask = (const int*)  d_in[4];
    const float* Wqkv = (const float*)d_in[5];
    const float* Wrel = (const float*)d_in[6];
    const float* Wout = (const float*)d_in[7];
    const float* gam  = (const float*)d_in[8];
    const float* bet  = (const float*)d_in[9];
    float* out = (float*)d_out;

    // ---- workspace layout (bf16 = u16), 81.8 MB total, with aliasing ----
    u16* whb   = (u16*)d_ws;                 // [4096][3072] bf16 (25.2 MB)
    u16* ctxb  = whb;                        //   alias: [4096][1024] bf16 (8.4 MB)
    float* ao  = (float*)(whb + 4194304);    //   alias: [4096][1024] f32 (16.8 MB)
    u16* rk_b  = whb + 12582912;             // [2048][1024] bf16
    u16* qrw_b = rk_b + 2097152;             // [BH][S][64]
    u16* qrr_b = qrw_b + 4194304;
    u16* kb    = qrr_b + 4194304;
    u16* vbT   = kb + 4194304;               // [BH][64][S]
    u16* rkb   = vbT + 4194304;              // [NHEAD][S][64]
    u16* xb    = rkb + 2097152;              // [4096][1024] bf16 (8.4 MB)
    u16* rposb = xb;                         //   alias after qkv GEMM (4.2 MB)
    u16* Wrelt = xb + 2097152;               //   alias (2.1 MB)
    u16* Woutt = Wrelt + 1048576;            //   alias (2.1 MB)
    u16* Wqkvt = xb + 4194304;               // [3072][1024] bf16 (6.3 MB)

    dim3 blk(256);
    // 1. cast x, transpose Wqkv, qkv GEMM (bf16 out)
    cast_f32_bf16<<<dim3(4096), blk, 0, stream>>>(x, xb);
    transp_cast<<<dim3(48, 16), blk, 0, stream>>>(Wqkv, Wqkvt, DMODEL, 3 * DMODEL);
    gemm_bf16<<<dim3(24, 32), blk, 0, stream>>>(xb, Wqkvt, nullptr, whb,
                                                NBATCH * S_LEN, 3 * DMODEL, DMODEL);
    // 2. rel projection (xb region is now dead -> reuse for rposb/Wrelt/Woutt)
    cast_f32_bf16<<<dim3(2048), blk, 0, stream>>>(rpos, rposb);
    transp_cast<<<dim3(16, 16), blk, 0, stream>>>(Wrel, Wrelt, DMODEL, DMODEL);
    transp_cast<<<dim3(16, 16), blk, 0, stream>>>(Wout, Woutt, DMODEL, DMODEL);
    gemm_bf16<<<dim3(8, 16), blk, 0, stream>>>(rposb, Wrelt, nullptr, rk_b,
                                               S_LEN, DMODEL, DMODEL);
    // 3. head-major repack
    prep_qkv<<<dim3(NBATCH * S_LEN), blk, 0, stream>>>(whb, rwb, rrb,
                                                       qrw_b, qrr_b, kb, vbT);
    prep_rk<<<dim3(S_LEN), blk, 0, stream>>>(rk_b, rkb);
    // 4. fused attention (whb dead -> ctxb aliases it)
    flash_attn<<<dim3(S_LEN / 64, NBATCH * NHEAD), blk, 0, stream>>>(
        qrw_b, qrr_b, kb, vbT, rkb, mask, ctxb);
    // 5. output projection (fp32 out)
    gemm_bf16<<<dim3(8, 32), blk, 0, stream>>>(ctxb, Woutt, ao, nullptr,
                                               NBATCH * S_LEN, DMODEL, DMODEL);
    // 6. residual + layernorm
    ln_kernel<<<dim3(NBATCH * S_LEN), blk, 0, stream>>>(x, ao, gam, bet, out);
}

// Round 4
// 404.013 us; speedup vs baseline: 10.9333x; 1.4879x over previous
//
#include <hip/hip_runtime.h>
#include <hip/hip_bf16.h>
#include <math.h>

#define S_LEN 2048
#define NHEAD 16
#define DHEAD 64
#define DMODEL 1024
#define NBATCH 2

typedef unsigned short u16;
typedef __attribute__((ext_vector_type(8))) short bf16x8;
typedef __attribute__((ext_vector_type(4))) short short4v;
typedef __attribute__((ext_vector_type(4))) float f32x4;

__device__ __forceinline__ short f2bs(float x) {
    __hip_bfloat16 h = __float2bfloat16(x);
    return __builtin_bit_cast(short, h);
}
__device__ __forceinline__ float bs2f(u16 u) {
    unsigned int x = ((unsigned int)u) << 16;
    return __builtin_bit_cast(float, x);
}

#define GL2LDS(g, l)                                                         \
    __builtin_amdgcn_global_load_lds(                                        \
        (const __attribute__((address_space(1))) void*)(g),                  \
        (__attribute__((address_space(3))) void*)(l), 16, 0, 0)

// ---------------------------------------------------------------------------
// fp32 -> bf16 flat cast. grid = n/1024.
// ---------------------------------------------------------------------------
__global__ __launch_bounds__(256) void cast_f32_bf16(const float* __restrict__ in,
                                                     u16* __restrict__ out) {
    const int i = (blockIdx.x * 256 + threadIdx.x) * 4;
    float4 v = *(const float4*)(in + i);
    short4v t;
    t[0] = f2bs(v.x); t[1] = f2bs(v.y); t[2] = f2bs(v.z); t[3] = f2bs(v.w);
    *(short4v*)(out + i) = t;
}

// ---------------------------------------------------------------------------
// W [K][N] fp32 -> Wt [N][K] bf16 (transpose + cast). grid = (N/64, K/64)
// ---------------------------------------------------------------------------
__global__ __launch_bounds__(256) void transp_cast(const float* __restrict__ W,
                                                   u16* __restrict__ Wt,
                                                   int K, int N) {
    __shared__ float t[64][65];
    const int k0 = blockIdx.y * 64, n0 = blockIdx.x * 64;
    const int r = threadIdx.x >> 4;
    const int c4 = (threadIdx.x & 15) * 4;
    #pragma unroll
    for (int it = 0; it < 4; ++it) {
        float4 v = *(const float4*)(W + (size_t)(k0 + it * 16 + r) * N + n0 + c4);
        t[c4 + 0][it * 16 + r] = v.x;
        t[c4 + 1][it * 16 + r] = v.y;
        t[c4 + 2][it * 16 + r] = v.z;
        t[c4 + 3][it * 16 + r] = v.w;
    }
    __syncthreads();
    #pragma unroll
    for (int it = 0; it < 4; ++it) {
        const int nn = it * 16 + r;
        short4v o;
        o[0] = f2bs(t[nn][c4 + 0]); o[1] = f2bs(t[nn][c4 + 1]);
        o[2] = f2bs(t[nn][c4 + 2]); o[3] = f2bs(t[nn][c4 + 3]);
        *(short4v*)(Wt + (size_t)(n0 + nn) * K + k0 + c4) = o;
    }
}

// ---------------------------------------------------------------------------
// bf16 MFMA GEMM: C[M,N] = A[M,K] @ Bt[N,K]^T (m97 structure).
// ---------------------------------------------------------------------------
__global__ __launch_bounds__(256, 2) void gemm_bf16(
    const u16* __restrict__ A, const u16* __restrict__ Bt,
    float* __restrict__ Cf, u16* __restrict__ Cb,
    int M, int N, int K)
{
    __shared__ u16 As[128 * 64];
    __shared__ u16 Bs[128 * 64];
    const int tid = threadIdx.x;
    const int lane = tid & 63;
    const int w = tid >> 6;
    const int quad = lane >> 4, col = lane & 15;
    const int bm = blockIdx.y * 128, bn = blockIdx.x * 128;
    const int wm = (w >> 1) * 64, wn = (w & 1) * 64;

    f32x4 acc[4][4];
    #pragma unroll
    for (int mt = 0; mt < 4; ++mt)
        #pragma unroll
        for (int nt = 0; nt < 4; ++nt) acc[mt][nt] = (f32x4){0.f, 0.f, 0.f, 0.f};

    for (int k0 = 0; k0 < K; k0 += 64) {
        #pragma unroll
        for (int it = 0; it < 4; ++it) {
            const int cb = it * 256 + w * 64;
            const int c = cb + lane;
            const int r = c >> 3;
            const int o = ((c & 7) ^ (r & 7)) * 8;
            GL2LDS(A + (size_t)(bm + r) * K + k0 + o, As + (size_t)cb * 8);
            GL2LDS(Bt + (size_t)(bn + r) * K + k0 + o, Bs + (size_t)cb * 8);
        }
        __syncthreads();
        #pragma unroll
        for (int kc = 0; kc < 2; ++kc) {
            bf16x8 af[4], bfr[4];
            #pragma unroll
            for (int t = 0; t < 4; ++t) {
                const int am = wm + t * 16 + col;
                const int aj = kc * 4 + quad;
                af[t] = *(const bf16x8*)&As[(size_t)am * 64 + ((aj ^ (am & 7)) * 8)];
                const int bn2 = wn + t * 16 + col;
                bfr[t] = *(const bf16x8*)&Bs[(size_t)bn2 * 64 + ((aj ^ (bn2 & 7)) * 8)];
            }
            #pragma unroll
            for (int mt = 0; mt < 4; ++mt)
                #pragma unroll
                for (int nt = 0; nt < 4; ++nt)
                    acc[mt][nt] = __builtin_amdgcn_mfma_f32_16x16x32_bf16(
                        af[mt], bfr[nt], acc[mt][nt], 0, 0, 0);
        }
        __syncthreads();
    }

    if (Cb) {
        #pragma unroll
        for (int mt = 0; mt < 4; ++mt)
            #pragma unroll
            for (int nt = 0; nt < 4; ++nt)
                #pragma unroll
                for (int r = 0; r < 4; ++r) {
                    const int row = bm + wm + mt * 16 + quad * 4 + r;
                    const int cn = bn + wn + nt * 16 + col;
                    Cb[(size_t)row * N + cn] = (u16)f2bs(acc[mt][nt][r]);
                }
    } else {
        #pragma unroll
        for (int mt = 0; mt < 4; ++mt)
            #pragma unroll
            for (int nt = 0; nt < 4; ++nt)
                #pragma unroll
                for (int r = 0; r < 4; ++r) {
                    const int row = bm + wm + mt * 16 + quad * 4 + r;
                    const int cn = bn + wn + nt * 16 + col;
                    Cf[(size_t)row * N + cn] = acc[mt][nt][r];
                }
    }
}

// ---------------------------------------------------------------------------
// Repack wh_b (bf16 [B,S,3*1024]) into head-major bf16 tensors.
// ---------------------------------------------------------------------------
__global__ __launch_bounds__(256) void prep_qkv(
    const u16* __restrict__ wh,
    const float* __restrict__ rwb, const float* __restrict__ rrb,
    u16* __restrict__ qrw_b, u16* __restrict__ qrr_b,
    u16* __restrict__ kb, u16* __restrict__ vbT)
{
    const int bs = blockIdx.x;
    const int b = bs >> 11, s = bs & 2047;
    const int e0 = threadIdx.x * 4;
    const int h = e0 >> 6, d = e0 & 63;
    const int bh = b * NHEAD + h;
    const u16* base = wh + (size_t)bs * 3 * DMODEL + e0;
    short4v q = *(const short4v*)(base);
    short4v k = *(const short4v*)(base + DMODEL);
    short4v v = *(const short4v*)(base + 2 * DMODEL);
    float4 bw = *(const float4*)(rwb + e0);
    float4 br = *(const float4*)(rrb + e0);
    const size_t o = ((size_t)bh * S_LEN + s) * 64 + d;
    short4v t;
    t[0] = f2bs(bs2f((u16)q[0]) + bw.x); t[1] = f2bs(bs2f((u16)q[1]) + bw.y);
    t[2] = f2bs(bs2f((u16)q[2]) + bw.z); t[3] = f2bs(bs2f((u16)q[3]) + bw.w);
    *(short4v*)(qrw_b + o) = t;
    t[0] = f2bs(bs2f((u16)q[0]) + br.x); t[1] = f2bs(bs2f((u16)q[1]) + br.y);
    t[2] = f2bs(bs2f((u16)q[2]) + br.z); t[3] = f2bs(bs2f((u16)q[3]) + br.w);
    *(short4v*)(qrr_b + o) = t;
    *(short4v*)(kb + o) = k;
    const size_t vo = ((size_t)bh * 64 + d) * S_LEN + s;
    vbT[vo + 0 * S_LEN] = (u16)v[0];
    vbT[vo + 1 * S_LEN] = (u16)v[1];
    vbT[vo + 2 * S_LEN] = (u16)v[2];
    vbT[vo + 3 * S_LEN] = (u16)v[3];
}

// rk_b bf16 [S,1024] -> rkb bf16 [NHEAD][S][64]
__global__ __launch_bounds__(256) void prep_rk(const u16* __restrict__ rk_b,
                                               u16* __restrict__ rkb) {
    const int l = blockIdx.x;
    const int e0 = threadIdx.x * 4;
    const int h = e0 >> 6, d = e0 & 63;
    short4v v = *(const short4v*)(rk_b + (size_t)l * DMODEL + e0);
    *(short4v*)(rkb + ((size_t)h * S_LEN + l) * 64 + d) = v;
}

// ---------------------------------------------------------------------------
// MFMA bf16 flash attention v3: all B-operands (K/V/rk) staged in LDS via
// async global_load_lds, shared by the block's 4 waves. XOR-swizzled LDS
// (bank = 4*(aj^(col&7)), 2-way = free). No-max online softmax (scores
// bounded), additive mask (-16384 -> exp==0), lane-local l, one final
// butterfly. rk panel: both regions collapse to row m = u + 48 - 16w over a
// 128-row panel; boundary step (dblk==0) adds a direct-VGPR region-2 pass.
// ---------------------------------------------------------------------------
__global__ __launch_bounds__(256, 3) void flash_attn(
    const u16* __restrict__ qrw_b, const u16* __restrict__ qrr_b,
    const u16* __restrict__ kb, const u16* __restrict__ vbT,
    const u16* __restrict__ rkb, const int* __restrict__ mask,
    u16* __restrict__ ctxb)
{
    const int lane = threadIdx.x & 63;
    const int w    = threadIdx.x >> 6;
    const int quad = lane >> 4;
    const int col  = lane & 15;
    const int bh   = blockIdx.y;
    const int b    = bh >> 4;
    const int n    = bh & 15;
    const int B0   = blockIdx.x * 64;
    const int iw0  = B0 + w * 16;

    __shared__ u16 Ks[64 * 64];     // XOR-swizzled: LDS[r][j] = G[r][j^(r&7)]
    __shared__ u16 Vs[64 * 64];
    __shared__ u16 Rs[128 * 64];    // rk panel, same swizzle
    __shared__ u16 Pr[4][16][72];   // per-wave P row-major, pad->2-way banks
    __shared__ float madd[S_LEN];   // additive mask table

    const size_t headQ = (size_t)bh * S_LEN * 64;
    const size_t headR = (size_t)n  * S_LEN * 64;

    for (int i = threadIdx.x; i < S_LEN; i += 256)
        madd[i] = mask[b * S_LEN + i] ? -16384.f : 0.f;

    // persistent Q A-fragments: lane holds A[m=col][k=quad*8+j (+32*kc)]
    bf16x8 a_rw[2], a_rr0[2], a_rr1[2];
    {
        const int r0 = iw0 + col;
        const int r1 = (r0 + 1 < S_LEN) ? (r0 + 1) : (S_LEN - 1);
        #pragma unroll
        for (int kc = 0; kc < 2; ++kc) {
            const int doff = kc * 32 + quad * 8;
            a_rw[kc]  = *(const bf16x8*)(qrw_b + headQ + (size_t)r0 * 64 + doff);
            a_rr0[kc] = *(const bf16x8*)(qrr_b + headQ + (size_t)r0 * 64 + doff);
            a_rr1[kc] = *(const bf16x8*)(qrr_b + headQ + (size_t)r1 * 64 + doff);
        }
    }

    f32x4 O[4];
    float l_acc[4] = {0.f, 0.f, 0.f, 0.f};
    #pragma unroll
    for (int dt = 0; dt < 4; ++dt) O[dt] = (f32x4){0.f, 0.f, 0.f, 0.f};

    const int swz  = ((lane & 7) ^ ((lane >> 3) & 7)) * 8;  // staging col offset
    const int lrow = lane >> 3;                             // row within 8-row chunk
    const int csel = col & 7;                               // readback swizzle key

    for (int u0 = 0; u0 < S_LEN; u0 += 64) {
        const int dblk = B0 - u0;                // block-uniform, multiple of 64
        __syncthreads();                         // prior step's LDS reads done
        // ---- async stage K (8 chunks), V (8), rk panel (16) ----
        #pragma unroll
        for (int t = 0; t < 2; ++t) {
            const int c = w * 2 + t;
            GL2LDS(kb + headQ + (size_t)(u0 + c * 8 + lrow) * 64 + swz, Ks + c * 512);
            GL2LDS(vbT + ((size_t)bh * 64 + c * 8 + lrow) * S_LEN + u0 + swz, Vs + c * 512);
        }
        const int pbase = (dblk >= 0) ? (S_LEN - 64 - dblk) : (-dblk - 65);
        #pragma unroll
        for (int t = 0; t < 4; ++t) {
            const int c = w * 4 + t;
            int rr = pbase + c * 8 + lrow;
            rr = rr < 0 ? 0 : (rr > S_LEN - 1 ? S_LEN - 1 : rr);
            GL2LDS(rkb + headR + (size_t)rr * 64 + swz, Rs + c * 512);
        }
        // boundary step: direct-VGPR loads for region 2 (in flight over barrier)
        bf16x8 rf2[5][2];
        if (dblk == 0) {
            const int c2w = -17 - 16 * w;
            #pragma unroll
            for (int g = 0; g < 5; ++g) {
                int row = c2w + g * 16 + col;
                row = row < 0 ? 0 : row;
                const u16* rb = rkb + headR + (size_t)row * 64 + quad * 8;
                rf2[g][0] = *(const bf16x8*)(rb);
                rf2[g][1] = *(const bf16x8*)(rb + 32);
            }
        }
        __syncthreads();                         // staging visible (vmcnt drained)

        // ---- ac = Qrw . K^T ----
        f32x4 sc[4];
        #pragma unroll
        for (int nt = 0; nt < 4; ++nt) {
            const int m = nt * 16 + col;
            bf16x8 k0 = *(const bf16x8*)&Ks[m * 64 + ((quad ^ csel) * 8)];
            bf16x8 k1 = *(const bf16x8*)&Ks[m * 64 + (((4 + quad) ^ csel) * 8)];
            f32x4 c = (f32x4){0.f, 0.f, 0.f, 0.f};
            c = __builtin_amdgcn_mfma_f32_16x16x32_bf16(a_rw[0], k0, c, 0, 0, 0);
            c = __builtin_amdgcn_mfma_f32_16x16x32_bf16(a_rw[1], k1, c, 0, 0, 0);
            sc[nt] = c;
        }

        // ---- bd diagonal GEMM from the panel ----
        f32x4 g1[5];
        {
            const bf16x8* aA = (dblk >= 0) ? a_rr0 : a_rr1;
            #pragma unroll
            for (int g = 0; g < 5; ++g) {
                const int m = g * 16 + col + 48 - 16 * w;   // m&7 == col&7
                bf16x8 r0 = *(const bf16x8*)&Rs[m * 64 + ((quad ^ csel) * 8)];
                bf16x8 r1 = *(const bf16x8*)&Rs[m * 64 + (((4 + quad) ^ csel) * 8)];
                f32x4 c = (f32x4){0.f, 0.f, 0.f, 0.f};
                c = __builtin_amdgcn_mfma_f32_16x16x32_bf16(aA[0], r0, c, 0, 0, 0);
                c = __builtin_amdgcn_mfma_f32_16x16x32_bf16(aA[1], r1, c, 0, 0, 0);
                g1[g] = c;
            }
        }
        if (dblk == 0) {
            // region-2 GEMM + 3-way merge (one step per block)
            const int lim1 = 15 + 16 * w;
            #pragma unroll
            for (int g = 0; g < 5; ++g) {
                f32x4 c = (f32x4){0.f, 0.f, 0.f, 0.f};
                c = __builtin_amdgcn_mfma_f32_16x16x32_bf16(a_rr1[0], rf2[g][0], c, 0, 0, 0);
                c = __builtin_amdgcn_mfma_f32_16x16x32_bf16(a_rr1[1], rf2[g][1], c, 0, 0, 0);
                const int u = g * 16 + col;
                #pragma unroll
                for (int r = 0; r < 4; ++r)
                    g1[g][r] = (u <= lim1) ? g1[g][r] : ((u == lim1 + 1) ? 0.f : c[r]);
            }
        } else {
            // single-region: zero column u == 16 + dblk + 16w (rare; wave-uniform)
            const int uz = 16 + dblk + 16 * w;
            if (uz >= 0 && uz < 80) {
                #pragma unroll
                for (int g = 0; g < 5; ++g)
                    if (g * 16 + col == uz) {
                        #pragma unroll
                        for (int r = 0; r < 4; ++r) g1[g][r] = 0.f;
                    }
            }
        }

        // ---- extract diagonal, add ac, scale, mask, exp, accumulate l ----
        #pragma unroll
        for (int nt = 0; nt < 4; ++nt) {
            const float ma = madd[u0 + nt * 16 + col];
            #pragma unroll
            for (int r = 0; r < 4; ++r) {
                const int uo = col + 15 - quad * 4 - r;      // [0,30]
                const int src = (quad << 4) | (uo & 15);
                float blo = __shfl(g1[nt][r], src, 64);
                float bhi = __shfl(g1[nt + 1][r], src, 64);
                float bd = (uo < 16) ? blo : bhi;
                float p = __expf(fmaf(sc[nt][r] + bd, 0.125f, ma));
                sc[nt][r] = p;
                l_acc[r] += p;
            }
        }

        // ---- P: C-layout -> LDS row-major -> A-frags ----
        #pragma unroll
        for (int nt = 0; nt < 4; ++nt)
            #pragma unroll
            for (int r = 0; r < 4; ++r)
                Pr[w][quad * 4 + r][nt * 16 + col] = (u16)f2bs(sc[nt][r]);
        bf16x8 pa[2];
        pa[0] = *(const bf16x8*)&Pr[w][col][quad * 8];
        pa[1] = *(const bf16x8*)&Pr[w][col][32 + quad * 8];

        // ---- O += P . V ----
        #pragma unroll
        for (int dt = 0; dt < 4; ++dt) {
            const int m = dt * 16 + col;
            bf16x8 v0 = *(const bf16x8*)&Vs[m * 64 + ((quad ^ csel) * 8)];
            bf16x8 v1 = *(const bf16x8*)&Vs[m * 64 + (((4 + quad) ^ csel) * 8)];
            f32x4 c = O[dt];
            c = __builtin_amdgcn_mfma_f32_16x16x32_bf16(pa[0], v0, c, 0, 0, 0);
            c = __builtin_amdgcn_mfma_f32_16x16x32_bf16(pa[1], v1, c, 0, 0, 0);
            O[dt] = c;
        }
    }

    // final row-sum reduction (once) + normalize + store
    float inv[4];
    #pragma unroll
    for (int r = 0; r < 4; ++r) {
        float s = l_acc[r];
        #pragma unroll
        for (int off = 1; off < 16; off <<= 1)
            s += __shfl_xor(s, off, 64);
        inv[r] = 1.f / s;
    }
    #pragma unroll
    for (int dt = 0; dt < 4; ++dt)
        #pragma unroll
        for (int r = 0; r < 4; ++r) {
            const int i = iw0 + quad * 4 + r;
            ctxb[((size_t)b * S_LEN + i) * DMODEL + n * 64 + dt * 16 + col] =
                (u16)f2bs(O[dt][r] * inv[r]);
        }
}

// ---------------------------------------------------------------------------
// out = LayerNorm(x + attn_out)
// ---------------------------------------------------------------------------
__global__ __launch_bounds__(256) void ln_kernel(const float* __restrict__ x,
                                                 const float* __restrict__ ao,
                                                 const float* __restrict__ gamma,
                                                 const float* __restrict__ beta,
                                                 float* __restrict__ out) {
    const int r = blockIdx.x;
    const int tid = threadIdx.x;
    const size_t base = (size_t)r * DMODEL + tid * 4;
    float4 xv = *(const float4*)(x + base);
    float4 av = *(const float4*)(ao + base);
    float v0 = xv.x + av.x, v1 = xv.y + av.y, v2 = xv.z + av.z, v3 = xv.w + av.w;

    float s = v0 + v1 + v2 + v3;
    #pragma unroll
    for (int off = 32; off > 0; off >>= 1) s += __shfl_xor(s, off, 64);
    __shared__ float red[4];
    __shared__ float red2[4];
    if ((tid & 63) == 0) red[tid >> 6] = s;
    __syncthreads();
    float mu = (red[0] + red[1] + red[2] + red[3]) * (1.0f / DMODEL);

    float d0 = v0 - mu, d1 = v1 - mu, d2 = v2 - mu, d3 = v3 - mu;
    float q = d0 * d0 + d1 * d1 + d2 * d2 + d3 * d3;
    #pragma unroll
    for (int off = 32; off > 0; off >>= 1) q += __shfl_xor(q, off, 64);
    if ((tid & 63) == 0) red2[tid >> 6] = q;
    __syncthreads();
    float var = (red2[0] + red2[1] + red2[2] + red2[3]) * (1.0f / DMODEL);
    float rstd = rsqrtf(var + 1e-5f);

    float4 g  = *(const float4*)(gamma + tid * 4);
    float4 be = *(const float4*)(beta + tid * 4);
    float4 o = make_float4(d0 * rstd * g.x + be.x,
                           d1 * rstd * g.y + be.y,
                           d2 * rstd * g.z + be.z,
                           d3 * rstd * g.w + be.w);
    *(float4*)(out + base) = o;
}

// ---------------------------------------------------------------------------
extern "C" void kernel_launch(void* const* d_in, const int* in_sizes, int n_in,
                              void* d_out, int out_size, void* d_ws, size_t ws_size,
                              hipStream_t stream) {
    const float* x    = (const float*)d_in[0];
    const float* rpos = (const float*)d_in[1];
    const float* rwb  = (const float*)d_in[2];
    const float* rrb  = (const float*)d_in[3];
    const int*   mask = (const int*)  d_in[4];
    const float* Wqkv = (const float*)d_in[5];
    const float* Wrel = (const float*)d_in[6];
    const float* Wout = (const float*)d_in[7];
    const float* gam  = (const float*)d_in[8];
    const float* bet  = (const float*)d_in[9];
    float* out = (float*)d_out;

    // ---- workspace layout (bf16 = u16), ~82 MB with aliasing ----
    u16* whb   = (u16*)d_ws;                 // [4096][3072] bf16
    u16* ctxb  = whb;                        //   alias after prep
    float* ao  = (float*)(whb + 4194304);    //   alias
    u16* rk_b  = whb + 12582912;
    u16* qrw_b = rk_b + 2097152;
    u16* qrr_b = qrw_b + 4194304;
    u16* kb    = qrr_b + 4194304;
    u16* vbT   = kb + 4194304;
    u16* rkb   = vbT + 4194304;
    u16* xb    = rkb + 2097152;
    u16* rposb = xb;
    u16* Wrelt = xb + 2097152;
    u16* Woutt = Wrelt + 1048576;
    u16* Wqkvt = xb + 4194304;

    dim3 blk(256);
    cast_f32_bf16<<<dim3(4096), blk, 0, stream>>>(x, xb);
    transp_cast<<<dim3(48, 16), blk, 0, stream>>>(Wqkv, Wqkvt, DMODEL, 3 * DMODEL);
    gemm_bf16<<<dim3(24, 32), blk, 0, stream>>>(xb, Wqkvt, nullptr, whb,
                                                NBATCH * S_LEN, 3 * DMODEL, DMODEL);
    cast_f32_bf16<<<dim3(2048), blk, 0, stream>>>(rpos, rposb);
    transp_cast<<<dim3(16, 16), blk, 0, stream>>>(Wrel, Wrelt, DMODEL, DMODEL);
    transp_cast<<<dim3(16, 16), blk, 0, stream>>>(Wout, Woutt, DMODEL, DMODEL);
    gemm_bf16<<<dim3(8, 16), blk, 0, stream>>>(rposb, Wrelt, nullptr, rk_b,
                                               S_LEN, DMODEL, DMODEL);
    prep_qkv<<<dim3(NBATCH * S_LEN), blk, 0, stream>>>(whb, rwb, rrb,
                                                       qrw_b, qrr_b, kb, vbT);
    prep_rk<<<dim3(S_LEN), blk, 0, stream>>>(rk_b, rkb);
    flash_attn<<<dim3(S_LEN / 64, NBATCH * NHEAD), blk, 0, stream>>>(
        qrw_b, qrr_b, kb, vbT, rkb, mask, ctxb);
    gemm_bf16<<<dim3(8, 32), blk, 0, stream>>>(ctxb, Woutt, ao, nullptr,
                                               NBATCH * S_LEN, DMODEL, DMODEL);
    ln_kernel<<<dim3(NBATCH * S_LEN), blk, 0, stream>>>(x, ao, gam, bet, out);
}

// Round 5
// 350.169 us; speedup vs baseline: 12.6144x; 1.1538x over previous
//
#include <hip/hip_runtime.h>
#include <hip/hip_bf16.h>
#include <math.h>

#define S_LEN 2048
#define NHEAD 16
#define DHEAD 64
#define DMODEL 1024
#define NBATCH 2

typedef unsigned short u16;
typedef __attribute__((ext_vector_type(8))) short bf16x8;
typedef __attribute__((ext_vector_type(4))) short short4v;
typedef __attribute__((ext_vector_type(4))) float f32x4;

__device__ __forceinline__ short f2bs(float x) {
    __hip_bfloat16 h = __float2bfloat16(x);
    return __builtin_bit_cast(short, h);
}

#define GL2LDS(g, l)                                                         \
    __builtin_amdgcn_global_load_lds(                                        \
        (const __attribute__((address_space(1))) void*)(g),                  \
        (__attribute__((address_space(3))) void*)(l), 16, 0, 0)

// ---------------------------------------------------------------------------
// fp32 -> bf16 flat cast. grid = n/1024.
// ---------------------------------------------------------------------------
__global__ __launch_bounds__(256) void cast_f32_bf16(const float* __restrict__ in,
                                                     u16* __restrict__ out) {
    const int i = (blockIdx.x * 256 + threadIdx.x) * 4;
    float4 v = *(const float4*)(in + i);
    short4v t;
    t[0] = f2bs(v.x); t[1] = f2bs(v.y); t[2] = f2bs(v.z); t[3] = f2bs(v.w);
    *(short4v*)(out + i) = t;
}

// ---------------------------------------------------------------------------
// W [K][N] fp32 -> Wt [N][K] bf16 (transpose + cast). grid = (N/64, K/64)
// ---------------------------------------------------------------------------
__global__ __launch_bounds__(256) void transp_cast(const float* __restrict__ W,
                                                   u16* __restrict__ Wt,
                                                   int K, int N) {
    __shared__ float t[64][65];
    const int k0 = blockIdx.y * 64, n0 = blockIdx.x * 64;
    const int r = threadIdx.x >> 4;
    const int c4 = (threadIdx.x & 15) * 4;
    #pragma unroll
    for (int it = 0; it < 4; ++it) {
        float4 v = *(const float4*)(W + (size_t)(k0 + it * 16 + r) * N + n0 + c4);
        t[c4 + 0][it * 16 + r] = v.x;
        t[c4 + 1][it * 16 + r] = v.y;
        t[c4 + 2][it * 16 + r] = v.z;
        t[c4 + 3][it * 16 + r] = v.w;
    }
    __syncthreads();
    #pragma unroll
    for (int it = 0; it < 4; ++it) {
        const int nn = it * 16 + r;
        short4v o;
        o[0] = f2bs(t[nn][c4 + 0]); o[1] = f2bs(t[nn][c4 + 1]);
        o[2] = f2bs(t[nn][c4 + 2]); o[3] = f2bs(t[nn][c4 + 3]);
        *(short4v*)(Wt + (size_t)(n0 + nn) * K + k0 + c4) = o;
    }
}

// ---------------------------------------------------------------------------
// Shared GEMM main-loop macro: 128x128 tile, BK=64, XOR-swizzled LDS,
// global_load_lds width-16. Leaves acc[4][4] (f32x4) computed.
// ---------------------------------------------------------------------------
#define GEMM_BODY(Aptr, Btptr, Kdim)                                          \
    __shared__ u16 As[128 * 64];                                              \
    __shared__ u16 Bs[128 * 64];                                              \
    const int tid = threadIdx.x;                                              \
    const int lane = tid & 63;                                                \
    const int w = tid >> 6;                                                   \
    const int quad = lane >> 4, col = lane & 15;                              \
    const int bm = blockIdx.y * 128, bn = blockIdx.x * 128;                   \
    const int wm = (w >> 1) * 64, wn = (w & 1) * 64;                          \
    f32x4 acc[4][4];                                                          \
    _Pragma("unroll")                                                         \
    for (int mt = 0; mt < 4; ++mt)                                            \
        _Pragma("unroll")                                                     \
        for (int nt = 0; nt < 4; ++nt) acc[mt][nt] = (f32x4){0.f,0.f,0.f,0.f};\
    for (int k0 = 0; k0 < (Kdim); k0 += 64) {                                 \
        _Pragma("unroll")                                                     \
        for (int it = 0; it < 4; ++it) {                                      \
            const int cb = it * 256 + w * 64;                                 \
            const int c = cb + lane;                                          \
            const int r = c >> 3;                                             \
            const int o = ((c & 7) ^ (r & 7)) * 8;                            \
            GL2LDS((Aptr) + (size_t)(bm + r) * (Kdim) + k0 + o, As + (size_t)cb * 8); \
            GL2LDS((Btptr) + (size_t)(bn + r) * (Kdim) + k0 + o, Bs + (size_t)cb * 8);\
        }                                                                     \
        __syncthreads();                                                      \
        _Pragma("unroll")                                                     \
        for (int kc = 0; kc < 2; ++kc) {                                      \
            bf16x8 af[4], bfr[4];                                             \
            _Pragma("unroll")                                                 \
            for (int t = 0; t < 4; ++t) {                                     \
                const int am = wm + t * 16 + col;                             \
                const int aj = kc * 4 + quad;                                 \
                af[t] = *(const bf16x8*)&As[(size_t)am * 64 + ((aj ^ (am & 7)) * 8)]; \
                const int bn2 = wn + t * 16 + col;                            \
                bfr[t] = *(const bf16x8*)&Bs[(size_t)bn2 * 64 + ((aj ^ (bn2 & 7)) * 8)]; \
            }                                                                 \
            _Pragma("unroll")                                                 \
            for (int mt = 0; mt < 4; ++mt)                                    \
                _Pragma("unroll")                                             \
                for (int nt = 0; nt < 4; ++nt)                                \
                    acc[mt][nt] = __builtin_amdgcn_mfma_f32_16x16x32_bf16(    \
                        af[mt], bfr[nt], acc[mt][nt], 0, 0, 0);               \
        }                                                                     \
        __syncthreads();                                                      \
    }

// ---------------------------------------------------------------------------
// qkv GEMM with fused head-major scatter epilogue (+q biases).
// A = xb [4096,1024], Bt = Wqkvt [3072,1024]. Grid (24, 32).
// ---------------------------------------------------------------------------
__global__ __launch_bounds__(256, 2) void gemm_qkv(
    const u16* __restrict__ A, const u16* __restrict__ Bt,
    const float* __restrict__ rwb, const float* __restrict__ rrb,
    u16* __restrict__ qrw_b, u16* __restrict__ qrr_b,
    u16* __restrict__ kb, u16* __restrict__ vbT)
{
    GEMM_BODY(A, Bt, DMODEL)
    #pragma unroll
    for (int mt = 0; mt < 4; ++mt) {
        const int row0 = bm + wm + mt * 16 + quad * 4;
        const int b = row0 >> 11;
        const int s0 = row0 & 2047;
        #pragma unroll
        for (int nt = 0; nt < 4; ++nt) {
            const int cn = bn + wn + nt * 16 + col;     // [0,3072)
            const int sec = cn >> 10;                   // wave-uniform per nt
            const int cc = cn & 1023;
            const int h = cc >> 6, d = cc & 63;
            const int bh = b * NHEAD + h;
            if (sec == 0) {
                const float bw = rwb[cc], br = rrb[cc];
                #pragma unroll
                for (int r = 0; r < 4; ++r) {
                    const size_t o = ((size_t)bh * S_LEN + s0 + r) * 64 + d;
                    qrw_b[o] = (u16)f2bs(acc[mt][nt][r] + bw);
                    qrr_b[o] = (u16)f2bs(acc[mt][nt][r] + br);
                }
            } else if (sec == 1) {
                #pragma unroll
                for (int r = 0; r < 4; ++r)
                    kb[((size_t)bh * S_LEN + s0 + r) * 64 + d] =
                        (u16)f2bs(acc[mt][nt][r]);
            } else {
                short4v t;
                t[0] = f2bs(acc[mt][nt][0]); t[1] = f2bs(acc[mt][nt][1]);
                t[2] = f2bs(acc[mt][nt][2]); t[3] = f2bs(acc[mt][nt][3]);
                *(short4v*)(vbT + ((size_t)bh * 64 + d) * S_LEN + s0) = t;
            }
        }
    }
}

// ---------------------------------------------------------------------------
// rel GEMM with fused head-major scatter: rkb [NHEAD][S][64]. Grid (8,16).
// ---------------------------------------------------------------------------
__global__ __launch_bounds__(256, 2) void gemm_rel(
    const u16* __restrict__ A, const u16* __restrict__ Bt,
    u16* __restrict__ rkb)
{
    GEMM_BODY(A, Bt, DMODEL)
    #pragma unroll
    for (int mt = 0; mt < 4; ++mt) {
        const int l0 = bm + wm + mt * 16 + quad * 4;
        #pragma unroll
        for (int nt = 0; nt < 4; ++nt) {
            const int cn = bn + wn + nt * 16 + col;
            const int h = cn >> 6, d = cn & 63;
            #pragma unroll
            for (int r = 0; r < 4; ++r)
                rkb[((size_t)h * S_LEN + l0 + r) * 64 + d] =
                    (u16)f2bs(acc[mt][nt][r]);
        }
    }
}

// ---------------------------------------------------------------------------
// Generic bf16 GEMM, fp32 output: C = A @ Bt^T (out-projection).
// ---------------------------------------------------------------------------
__global__ __launch_bounds__(256, 2) void gemm_out(
    const u16* __restrict__ A, const u16* __restrict__ Bt,
    float* __restrict__ Cf, int N, int K)
{
    GEMM_BODY(A, Bt, K)
    #pragma unroll
    for (int mt = 0; mt < 4; ++mt)
        #pragma unroll
        for (int nt = 0; nt < 4; ++nt)
            #pragma unroll
            for (int r = 0; r < 4; ++r) {
                const int row = bm + wm + mt * 16 + quad * 4 + r;
                const int cn = bn + wn + nt * 16 + col;
                Cf[(size_t)row * N + cn] = acc[mt][nt][r];
            }
}

// ---------------------------------------------------------------------------
// MFMA bf16 flash attention v4: Q-tile 128, 8 waves (512 thr) share one
// K/V/rk LDS staging step -> half the barrier-steps of v3, half the staging
// traffic per q-row. Analytic rel-shift via 192-row rk panel
// (m = u + 112 - 16w); per-wave delta = dblk+16w; mixed waves (0<=delta<=48,
// only in steps dblk in {0,-64}) add a direct-VGPR pass for the other region.
// Unified 3-way select: u<=15+delta -> R1; ==16+delta -> 0; else R2.
// No-max softmax (bounded scores), additive -16384 mask, lane-local l.
// ---------------------------------------------------------------------------
__global__ __launch_bounds__(512, 2) void flash_attn(
    const u16* __restrict__ qrw_b, const u16* __restrict__ qrr_b,
    const u16* __restrict__ kb, const u16* __restrict__ vbT,
    const u16* __restrict__ rkb, const int* __restrict__ mask,
    u16* __restrict__ ctxb)
{
    const int lane = threadIdx.x & 63;
    const int w    = threadIdx.x >> 6;      // 0..7
    const int quad = lane >> 4;
    const int col  = lane & 15;
    const int bh   = blockIdx.y;
    const int b    = bh >> 4;
    const int n    = bh & 15;
    const int B0   = blockIdx.x * 128;
    const int iw0  = B0 + w * 16;

    __shared__ u16 Ks[64 * 64];      // XOR-swizzled
    __shared__ u16 Vs[64 * 64];
    __shared__ u16 Rs[192 * 64];     // rk panel
    __shared__ u16 Pr[8][16][72];
    __shared__ float madd[S_LEN];

    const size_t headQ = (size_t)bh * S_LEN * 64;
    const size_t headR = (size_t)n  * S_LEN * 64;

    for (int i = threadIdx.x; i < S_LEN; i += 512)
        madd[i] = mask[b * S_LEN + i] ? -16384.f : 0.f;

    bf16x8 a_rw[2], a_rr0[2], a_rr1[2];
    {
        const int r0 = iw0 + col;
        const int r1 = (r0 + 1 < S_LEN) ? (r0 + 1) : (S_LEN - 1);
        #pragma unroll
        for (int kc = 0; kc < 2; ++kc) {
            const int doff = kc * 32 + quad * 8;
            a_rw[kc]  = *(const bf16x8*)(qrw_b + headQ + (size_t)r0 * 64 + doff);
            a_rr0[kc] = *(const bf16x8*)(qrr_b + headQ + (size_t)r0 * 64 + doff);
            a_rr1[kc] = *(const bf16x8*)(qrr_b + headQ + (size_t)r1 * 64 + doff);
        }
    }

    f32x4 O[4];
    float l_acc[4] = {0.f, 0.f, 0.f, 0.f};
    #pragma unroll
    for (int dt = 0; dt < 4; ++dt) O[dt] = (f32x4){0.f, 0.f, 0.f, 0.f};

    const int swz  = ((lane & 7) ^ ((lane >> 3) & 7)) * 8;
    const int lrow = lane >> 3;
    const int csel = col & 7;
    const int delta = B0 - 0 + 16 * w;   // updated per step below via dblk

    for (int u0 = 0; u0 < S_LEN; u0 += 64) {
        const int dblk = B0 - u0;                 // block-uniform, mult of 64
        const int dw = dblk + 16 * w;             // wave-uniform
        const bool mixed = (dw >= 0) && (dw <= 48);
        __syncthreads();
        // ---- stage K (8 chunks), V (8), rk panel (24); 5 chunks/wave ----
        const int pbase = (dblk >= 0) ? (S_LEN - 128 - dblk) : (-dblk - 129);
        #pragma unroll
        for (int t = 0; t < 5; ++t) {
            const int idx = w * 5 + t;
            if (idx < 8) {
                GL2LDS(kb + headQ + (size_t)(u0 + idx * 8 + lrow) * 64 + swz,
                       Ks + idx * 512);
            } else if (idx < 16) {
                const int c = idx - 8;
                GL2LDS(vbT + ((size_t)bh * 64 + c * 8 + lrow) * S_LEN + u0 + swz,
                       Vs + c * 512);
            } else {
                const int c = idx - 16;
                int rr = pbase + c * 8 + lrow;
                rr = rr < 0 ? 0 : (rr > S_LEN - 1 ? S_LEN - 1 : rr);
                GL2LDS(rkb + headR + (size_t)rr * 64 + swz, Rs + c * 512);
            }
        }
        // mixed waves: direct-VGPR loads of the other region (in flight over barrier)
        bf16x8 rf2[5][2];
        if (mixed) {
            #pragma unroll
            for (int g = 0; g < 5; ++g) {
                const int u = g * 16 + col;
                int row = (dblk >= 0) ? (u - dw - 17) : (S_LEN - 16 - dw + u);
                row = row < 0 ? 0 : (row > S_LEN - 1 ? S_LEN - 1 : row);
                const u16* rb = rkb + headR + (size_t)row * 64 + quad * 8;
                rf2[g][0] = *(const bf16x8*)(rb);
                rf2[g][1] = *(const bf16x8*)(rb + 32);
            }
        }
        __syncthreads();

        // ---- ac = Qrw . K^T ----
        f32x4 sc[4];
        #pragma unroll
        for (int nt = 0; nt < 4; ++nt) {
            const int m = nt * 16 + col;
            bf16x8 k0 = *(const bf16x8*)&Ks[m * 64 + ((quad ^ csel) * 8)];
            bf16x8 k1 = *(const bf16x8*)&Ks[m * 64 + (((4 + quad) ^ csel) * 8)];
            f32x4 c = (f32x4){0.f, 0.f, 0.f, 0.f};
            c = __builtin_amdgcn_mfma_f32_16x16x32_bf16(a_rw[0], k0, c, 0, 0, 0);
            c = __builtin_amdgcn_mfma_f32_16x16x32_bf16(a_rw[1], k1, c, 0, 0, 0);
            sc[nt] = c;
        }

        // ---- bd: panel GEMM (+ VGPR pass for mixed waves) ----
        f32x4 pnl[5], oth[5];
        {
            const bf16x8* aP = (dblk >= 0) ? a_rr0 : a_rr1;
            #pragma unroll
            for (int g = 0; g < 5; ++g) {
                const int m = g * 16 + col + 112 - 16 * w;   // m&7 == col&7
                bf16x8 r0 = *(const bf16x8*)&Rs[m * 64 + ((quad ^ csel) * 8)];
                bf16x8 r1 = *(const bf16x8*)&Rs[m * 64 + (((4 + quad) ^ csel) * 8)];
                f32x4 c = (f32x4){0.f, 0.f, 0.f, 0.f};
                c = __builtin_amdgcn_mfma_f32_16x16x32_bf16(aP[0], r0, c, 0, 0, 0);
                c = __builtin_amdgcn_mfma_f32_16x16x32_bf16(aP[1], r1, c, 0, 0, 0);
                pnl[g] = c;
            }
        }
        #pragma unroll
        for (int g = 0; g < 5; ++g) oth[g] = (f32x4){0.f, 0.f, 0.f, 0.f};
        if (mixed) {
            const bf16x8* aV = (dblk >= 0) ? a_rr1 : a_rr0;
            #pragma unroll
            for (int g = 0; g < 5; ++g) {
                f32x4 c = (f32x4){0.f, 0.f, 0.f, 0.f};
                c = __builtin_amdgcn_mfma_f32_16x16x32_bf16(aV[0], rf2[g][0], c, 0, 0, 0);
                c = __builtin_amdgcn_mfma_f32_16x16x32_bf16(aV[1], rf2[g][1], c, 0, 0, 0);
                oth[g] = c;
            }
        }
        // unified 3-way select into pnl[]
        const int lim1 = 15 + dw;
        #pragma unroll
        for (int g = 0; g < 5; ++g) {
            const int u = g * 16 + col;
            #pragma unroll
            for (int r = 0; r < 4; ++r) {
                const float r1v = (dblk >= 0) ? pnl[g][r] : oth[g][r];
                const float r2v = (dblk >= 0) ? oth[g][r] : pnl[g][r];
                pnl[g][r] = (u <= lim1) ? r1v : ((u == lim1 + 1) ? 0.f : r2v);
            }
        }

        // ---- extract diagonal, add ac, scale, mask, exp, accumulate l ----
        #pragma unroll
        for (int nt = 0; nt < 4; ++nt) {
            const float ma = madd[u0 + nt * 16 + col];
            #pragma unroll
            for (int r = 0; r < 4; ++r) {
                const int uo = col + 15 - quad * 4 - r;      // [0,30]
                const int src = (quad << 4) | (uo & 15);
                float blo = __shfl(pnl[nt][r], src, 64);
                float bhi = __shfl(pnl[nt + 1][r], src, 64);
                float bd = (uo < 16) ? blo : bhi;
                float p = __expf(fmaf(sc[nt][r] + bd, 0.125f, ma));
                sc[nt][r] = p;
                l_acc[r] += p;
            }
        }

        // ---- P: C-layout -> LDS row-major -> A-frags ----
        #pragma unroll
        for (int nt = 0; nt < 4; ++nt)
            #pragma unroll
            for (int r = 0; r < 4; ++r)
                Pr[w][quad * 4 + r][nt * 16 + col] = (u16)f2bs(sc[nt][r]);
        bf16x8 pa[2];
        pa[0] = *(const bf16x8*)&Pr[w][col][quad * 8];
        pa[1] = *(const bf16x8*)&Pr[w][col][32 + quad * 8];

        // ---- O += P . V ----
        #pragma unroll
        for (int dt = 0; dt < 4; ++dt) {
            const int m = dt * 16 + col;
            bf16x8 v0 = *(const bf16x8*)&Vs[m * 64 + ((quad ^ csel) * 8)];
            bf16x8 v1 = *(const bf16x8*)&Vs[m * 64 + (((4 + quad) ^ csel) * 8)];
            f32x4 c = O[dt];
            c = __builtin_amdgcn_mfma_f32_16x16x32_bf16(pa[0], v0, c, 0, 0, 0);
            c = __builtin_amdgcn_mfma_f32_16x16x32_bf16(pa[1], v1, c, 0, 0, 0);
            O[dt] = c;
        }
    }

    float inv[4];
    #pragma unroll
    for (int r = 0; r < 4; ++r) {
        float s = l_acc[r];
        #pragma unroll
        for (int off = 1; off < 16; off <<= 1)
            s += __shfl_xor(s, off, 64);
        inv[r] = 1.f / s;
    }
    #pragma unroll
    for (int dt = 0; dt < 4; ++dt)
        #pragma unroll
        for (int r = 0; r < 4; ++r) {
            const int i = iw0 + quad * 4 + r;
            ctxb[((size_t)b * S_LEN + i) * DMODEL + n * 64 + dt * 16 + col] =
                (u16)f2bs(O[dt][r] * inv[r]);
        }
}

// ---------------------------------------------------------------------------
// out = LayerNorm(x + attn_out)
// ---------------------------------------------------------------------------
__global__ __launch_bounds__(256) void ln_kernel(const float* __restrict__ x,
                                                 const float* __restrict__ ao,
                                                 const float* __restrict__ gamma,
                                                 const float* __restrict__ beta,
                                                 float* __restrict__ out) {
    const int r = blockIdx.x;
    const int tid = threadIdx.x;
    const size_t base = (size_t)r * DMODEL + tid * 4;
    float4 xv = *(const float4*)(x + base);
    float4 av = *(const float4*)(ao + base);
    float v0 = xv.x + av.x, v1 = xv.y + av.y, v2 = xv.z + av.z, v3 = xv.w + av.w;

    float s = v0 + v1 + v2 + v3;
    #pragma unroll
    for (int off = 32; off > 0; off >>= 1) s += __shfl_xor(s, off, 64);
    __shared__ float red[4];
    __shared__ float red2[4];
    if ((tid & 63) == 0) red[tid >> 6] = s;
    __syncthreads();
    float mu = (red[0] + red[1] + red[2] + red[3]) * (1.0f / DMODEL);

    float d0 = v0 - mu, d1 = v1 - mu, d2 = v2 - mu, d3 = v3 - mu;
    float q = d0 * d0 + d1 * d1 + d2 * d2 + d3 * d3;
    #pragma unroll
    for (int off = 32; off > 0; off >>= 1) q += __shfl_xor(q, off, 64);
    if ((tid & 63) == 0) red2[tid >> 6] = q;
    __syncthreads();
    float var = (red2[0] + red2[1] + red2[2] + red2[3]) * (1.0f / DMODEL);
    float rstd = rsqrtf(var + 1e-5f);

    float4 g  = *(const float4*)(gamma + tid * 4);
    float4 be = *(const float4*)(beta + tid * 4);
    float4 o = make_float4(d0 * rstd * g.x + be.x,
                           d1 * rstd * g.y + be.y,
                           d2 * rstd * g.z + be.z,
                           d3 * rstd * g.w + be.w);
    *(float4*)(out + base) = o;
}

// ---------------------------------------------------------------------------
extern "C" void kernel_launch(void* const* d_in, const int* in_sizes, int n_in,
                              void* d_out, int out_size, void* d_ws, size_t ws_size,
                              hipStream_t stream) {
    const float* x    = (const float*)d_in[0];
    const float* rpos = (const float*)d_in[1];
    const float* rwb  = (const float*)d_in[2];
    const float* rrb  = (const float*)d_in[3];
    const int*   mask = (const int*)  d_in[4];
    const float* Wqkv = (const float*)d_in[5];
    const float* Wrel = (const float*)d_in[6];
    const float* Wout = (const float*)d_in[7];
    const float* gam  = (const float*)d_in[8];
    const float* bet  = (const float*)d_in[9];
    float* out = (float*)d_out;

    // ---- workspace layout (u16 units), ~86 MB, no aliasing ----
    u16* wsb   = (u16*)d_ws;
    u16* ctxb  = wsb;                        // [4096][1024] bf16
    float* ao  = (float*)(wsb + 4194304);    // [4096][1024] f32
    u16* qrw_b = wsb + 12582912;             // [BH][S][64]
    u16* qrr_b = qrw_b + 4194304;
    u16* kb    = qrr_b + 4194304;
    u16* vbT   = kb + 4194304;               // [BH][64][S]
    u16* rkb   = vbT + 4194304;              // [NHEAD][S][64]
    u16* xb    = rkb + 2097152;              // [4096][1024]
    u16* rposb = xb + 4194304;               // [2048][1024]
    u16* Wqkvt = rposb + 2097152;            // [3072][1024]
    u16* Wrelt = Wqkvt + 3145728;            // [1024][1024]
    u16* Woutt = Wrelt + 1048576;            // [1024][1024]

    dim3 blk(256);
    cast_f32_bf16<<<dim3(4096), blk, 0, stream>>>(x, xb);
    transp_cast<<<dim3(48, 16), blk, 0, stream>>>(Wqkv, Wqkvt, DMODEL, 3 * DMODEL);
    gemm_qkv<<<dim3(24, 32), blk, 0, stream>>>(xb, Wqkvt, rwb, rrb,
                                               qrw_b, qrr_b, kb, vbT);
    cast_f32_bf16<<<dim3(2048), blk, 0, stream>>>(rpos, rposb);
    transp_cast<<<dim3(16, 16), blk, 0, stream>>>(Wrel, Wrelt, DMODEL, DMODEL);
    gemm_rel<<<dim3(8, 16), blk, 0, stream>>>(rposb, Wrelt, rkb);
    transp_cast<<<dim3(16, 16), blk, 0, stream>>>(Wout, Woutt, DMODEL, DMODEL);
    flash_attn<<<dim3(S_LEN / 128, NBATCH * NHEAD), dim3(512), 0, stream>>>(
        qrw_b, qrr_b, kb, vbT, rkb, mask, ctxb);
    gemm_out<<<dim3(8, 32), blk, 0, stream>>>(ctxb, Woutt, ao, DMODEL, DMODEL);
    ln_kernel<<<dim3(NBATCH * S_LEN), blk, 0, stream>>>(x, ao, gam, bet, out);
}